// Round 4
// baseline (2557.689 us; speedup 1.0000x reference)
//
#include <hip/hip_runtime.h>
#include <hip/hip_fp16.h>

#define NN 50000
#define NE 800000
#define HD 128
#define NSL 128          // edge slices
#define SLE (NE / NSL)   // 6250 edges per slice
#define PW  12500        // packed words per chunk (2 bins/word, 25000 bins/chunk)

typedef __attribute__((ext_vector_type(8))) short short8;
typedef __attribute__((ext_vector_type(4))) float f32x4;
typedef __attribute__((ext_vector_type(4))) unsigned u32x4;

__device__ inline unsigned bf2pack(float lo, float hi) {
    unsigned a = __float_as_uint(lo); a = (a + 0x7fffu + ((a >> 16) & 1u)) >> 16;
    unsigned b = __float_as_uint(hi); b = (b + 0x7fffu + ((b >> 16) & 1u)) >> 16;
    return a | (b << 16);
}

// packed edge: low 16 = src node, high 16 = fp16 weight
__device__ inline float edgw(unsigned p) {
    return __half2float(__ushort_as_half((unsigned short)(p >> 16)));
}

// ---------------------------------------------------------------------------
// Device-scope grid barrier (sense-reversing, monotonic phase numbers).
// Safe because every persistent kernel's grid is co-resident by construction
// (launch_bounds + grid <= blocks/CU * 256). bslot[0]=count, bslot[1]=sense.
// ---------------------------------------------------------------------------
__device__ __forceinline__ void gbar(int* bslot, int nblk, int ph) {
    __syncthreads();
    if (threadIdx.x == 0) {
        __threadfence();
        int prev = __hip_atomic_fetch_add(&bslot[0], 1, __ATOMIC_ACQ_REL,
                                          __HIP_MEMORY_SCOPE_AGENT);
        if (prev == nblk - 1) {
            __hip_atomic_store(&bslot[0], 0, __ATOMIC_RELAXED,
                               __HIP_MEMORY_SCOPE_AGENT);
            __hip_atomic_store(&bslot[1], ph, __ATOMIC_RELEASE,
                               __HIP_MEMORY_SCOPE_AGENT);
        } else {
            while (__hip_atomic_load(&bslot[1], __ATOMIC_ACQUIRE,
                                     __HIP_MEMORY_SCOPE_AGENT) < ph)
                __builtin_amdgcn_s_sleep(8);
        }
    }
    __syncthreads();
}

// ---------------------------------------------------------------------------
// BN finalize: gpart[256][512] -> ss[256] (scale, shift). One block, 256 thr.
// ---------------------------------------------------------------------------
__device__ void ss_reduce(const float* __restrict__ gpart, const float* __restrict__ gg,
                          const float* __restrict__ be, float* __restrict__ ss) {
    int t = threadIdx.x;
    int f = t >> 1, half = t & 1;
    const float4* sp = (const float4*)(gpart + (size_t)f * 512 + half * 256);
    const float4* qp = (const float4*)(gpart + (size_t)(128 + f) * 512 + half * 256);
    float s = 0.f, q = 0.f;
    #pragma unroll 8
    for (int i = 0; i < 64; i++) {
        float4 a = sp[i]; s += a.x + a.y + a.z + a.w;
        float4 c = qp[i]; q += c.x + c.y + c.z + c.w;
    }
    s += __shfl_xor(s, 1); q += __shfl_xor(q, 1);
    if (half == 0) {
        float mean = s * (1.0f / NN);
        float var = q * (1.0f / NN) - mean * mean;
        float sc = gg[f] * rsqrtf(var + 1e-5f);
        ss[f] = sc;
        ss[128 + f] = be[f] - mean * sc;
    }
}

// ---------------------------------------------------------------------------
// PREP (persistent, 512 blocks): hist -> hreduce | wconv -> scan -> bscan ->
// fill2. rowptr is block-local-exclusive; consumers add boff[i>>8].
// ---------------------------------------------------------------------------
__global__ __launch_bounds__(256, 2) void k_prep(
        const int* __restrict__ ei, float* __restrict__ dinv, int* __restrict__ cnt,
        int* __restrict__ rowptr, int* __restrict__ bsum, int* __restrict__ boff,
        unsigned* __restrict__ pre, unsigned* __restrict__ edg,
        const float* __restrict__ W2, const float* __restrict__ W3,
        const float* __restrict__ W4, unsigned short* __restrict__ Wb,
        unsigned* __restrict__ phist, int* __restrict__ bar) {
    __shared__ unsigned shb[PW];  // 50 KB, reused per phase
    const int b = blockIdx.x;
    const int tid = threadIdx.x;
    const int nblk = (int)gridDim.x;

    // P0: per-slice packed histogram (all 512 blocks)
    {
        int a = b >> 8, s = (b & 255) >> 1, c = b & 1;
        for (int i = tid; i < PW; i += 256) shb[i] = 0u;
        __syncthreads();
        const int* arr = ei + a * NE + s * SLE;
        int lo = c * 25000;
        for (int i = tid; i < SLE; i += 256) {
            int v = arr[i] - lo;
            if ((unsigned)v < 25000u)
                atomicAdd(&shb[v >> 1], 1u << ((v & 1) * 16));
        }
        __syncthreads();
        unsigned* dst = phist + (size_t)b * PW;
        for (int i = tid; i < PW; i += 256) dst[i] = shb[i];
    }
    gbar(bar, nblk, 1);

    // P1: hreduce (blocks 0..195) | weight swizzle (blocks 196..511)
    if (b < 196) {
        int idx = b * 256 + tid;
        if (idx < 50000) {
            int a = idx / 25000;
            int gw = idx % 25000;
            int c = gw / PW;
            int w = gw % PW;
            unsigned accLo = 0, accHi = 0;
            for (int s = 0; s < NSL; s++) {
                unsigned p = phist[(size_t)(((a * NSL + s) * 2 + c)) * PW + w];
                if (a == 1) pre[(size_t)s * 25000 + gw] = accLo | (accHi << 16);
                accLo += p & 0xffffu;
                accHi += p >> 16;
            }
            int b0 = c * 25000 + 2 * w;
            if (a == 0) {
                dinv[b0]     = accLo ? rsqrtf((float)accLo) : 0.0f;
                dinv[b0 + 1] = accHi ? rsqrtf((float)accHi) : 0.0f;
            } else {
                cnt[b0]     = (int)accLo;
                cnt[b0 + 1] = (int)accHi;
            }
        }
    } else {
        for (int gidx = (b - 196) * 256 + tid; gidx < 196608; gidx += 316 * 256) {
            int which = gidx >> 16;
            int idx = gidx & 65535;
            const float* W = which == 0 ? W2 : (which == 1 ? W3 : W4);
            int slot = idx >> 9;
            int lane = (idx >> 3) & 63;
            int j = idx & 7;
            int wg = slot >> 4;
            int t = slot & 15;
            int w = wg >> 1;
            int g = wg & 1;
            int k = t * 32 + (lane >> 4) * 8 + j;
            int col = w * 32 + g * 16 + (lane & 15);
            unsigned u = __float_as_uint(W[k * HD + col]);
            Wb[which * 65536 + idx] = (unsigned short)((u + 0x7fffu + ((u >> 16) & 1u)) >> 16);
        }
    }
    gbar(bar, nblk, 2);

    // P2: per-block (256-wide) exclusive scan of cnt
    if (b < 196) {
        int* si = (int*)shb;
        int gid = b * 256 + tid;
        int v = (gid < NN) ? cnt[gid] : 0;
        si[tid] = v;
        __syncthreads();
        for (int off = 1; off < 256; off <<= 1) {
            int t2 = 0;
            if (tid >= off) t2 = si[tid - off];
            __syncthreads();
            si[tid] += t2;
            __syncthreads();
        }
        if (gid < NN) rowptr[gid] = si[tid] - v;
        if (tid == 255) bsum[b] = si[255];
    }
    gbar(bar, nblk, 3);

    // P3: scan the 196 block sums (block 0)
    if (b == 0) {
        int* si = (int*)shb;
        int v = (tid < 196) ? bsum[tid] : 0;
        si[tid] = v;
        __syncthreads();
        for (int off = 1; off < 256; off <<= 1) {
            int t2 = 0;
            if (tid >= off) t2 = si[tid - off];
            __syncthreads();
            si[tid] += t2;
            __syncthreads();
        }
        if (tid < 196) boff[tid] = si[tid] - v;
        if (tid == 195) rowptr[NN] = NE - (si[195] - v);  // so RP(NN) == NE
    }
    gbar(bar, nblk, 4);

    // P4: fill edges in CSR order (blocks 0..255)
    if (b < 256) {
        int s = b >> 1, c = b & 1;
        for (int i = tid; i < PW; i += 256) shb[i] = 0u;
        __syncthreads();
        int lo = c * 25000;
        const unsigned* preS = pre + (size_t)s * 25000 + c * PW;
        for (int i = tid; i < SLE; i += 256) {
            int e = s * SLE + i;
            int d = ei[NE + e];
            int v = d - lo;
            if ((unsigned)v < 25000u) {
                int src = ei[e];
                int w = v >> 1;
                int sh = (v & 1) * 16;
                unsigned r = atomicAdd(&shb[w], 1u << sh);
                r = (r >> sh) & 0xffffu;
                unsigned pw = (preS[w] >> sh) & 0xffffu;
                int pos = rowptr[d] + boff[d >> 8] + (int)pw + (int)r;
                unsigned short hw = __half_as_ushort(__float2half(-dinv[src] * dinv[d]));
                edg[pos] = (unsigned)src | ((unsigned)hw << 16);
            }
        }
    }
}

// ---------------------------------------------------------------------------
// dim-3 propagation pass (device fn; node = blockIdx*256+tid, one shot)
// ---------------------------------------------------------------------------
__device__ void prop3_pass(const float* __restrict__ h, const float* __restrict__ sub,
                           const int* __restrict__ rowptr, const int* __restrict__ boff,
                           const unsigned* __restrict__ edg, float* __restrict__ out) {
    int node = blockIdx.x * 256 + threadIdx.x;
    if (node >= NN) return;
    int e0 = rowptr[node] + boff[node >> 8];
    int e1 = rowptr[node + 1] + boff[(node + 1) >> 8];
    float a0 = 0.f, a1 = 0.f, a2 = 0.f;
    float c0 = 0.f, c1 = 0.f, c2 = 0.f;
    int e = e0;
    for (; e + 4 <= e1; e += 4) {
        unsigned p0 = edg[e], p1 = edg[e + 1], p2 = edg[e + 2], p3 = edg[e + 3];
        int s0 = (int)(p0 & 0xffffu) * 3, s1 = (int)(p1 & 0xffffu) * 3;
        int s2 = (int)(p2 & 0xffffu) * 3, s3 = (int)(p3 & 0xffffu) * 3;
        float x0 = h[s0], y0 = h[s0 + 1], z0 = h[s0 + 2];
        float x1 = h[s1], y1 = h[s1 + 1], z1 = h[s1 + 2];
        float x2 = h[s2], y2 = h[s2 + 1], z2 = h[s2 + 2];
        float x3 = h[s3], y3 = h[s3 + 1], z3 = h[s3 + 2];
        float w0 = edgw(p0), w1 = edgw(p1), w2 = edgw(p2), w3 = edgw(p3);
        a0 = fmaf(w0, x0, a0); a1 = fmaf(w0, y0, a1); a2 = fmaf(w0, z0, a2);
        c0 = fmaf(w1, x1, c0); c1 = fmaf(w1, y1, c1); c2 = fmaf(w1, z1, c2);
        a0 = fmaf(w2, x2, a0); a1 = fmaf(w2, y2, a1); a2 = fmaf(w2, z2, a2);
        c0 = fmaf(w3, x3, c0); c1 = fmaf(w3, y3, c1); c2 = fmaf(w3, z3, c2);
    }
    if (e < e1) {  // masked 3-wide tail (packed 0 -> src 0, weight 0.0)
        unsigned p0 = edg[e];
        unsigned p1 = (e + 1 < e1) ? edg[e + 1] : 0u;
        unsigned p2 = (e + 2 < e1) ? edg[e + 2] : 0u;
        int s0 = (int)(p0 & 0xffffu) * 3, s1 = (int)(p1 & 0xffffu) * 3;
        int s2 = (int)(p2 & 0xffffu) * 3;
        float x0 = h[s0], y0 = h[s0 + 1], z0 = h[s0 + 2];
        float x1 = h[s1], y1 = h[s1 + 1], z1 = h[s1 + 2];
        float x2 = h[s2], y2 = h[s2 + 1], z2 = h[s2 + 2];
        float w0 = edgw(p0), w1 = edgw(p1), w2 = edgw(p2);
        a0 = fmaf(w0, x0, a0); a1 = fmaf(w0, y0, a1); a2 = fmaf(w0, z0, a2);
        c0 = fmaf(w1, x1, c0); c1 = fmaf(w1, y1, c1); c2 = fmaf(w1, z1, c2);
        a0 = fmaf(w2, x2, a0); a1 = fmaf(w2, y2, a1); a2 = fmaf(w2, z2, a2);
    }
    a0 += c0; a1 += c1; a2 += c2;
    if (sub) {
        a0 = 2.f * a0 - sub[node * 3 + 0];
        a1 = 2.f * a1 - sub[node * 3 + 1];
        a2 = 2.f * a2 - sub[node * 3 + 2];
    }
    out[node * 3 + 0] = a0;
    out[node * 3 + 1] = a1;
    out[node * 3 + 2] = a2;
}

// ---------------------------------------------------------------------------
// LAYER 1 (persistent, 512 blocks): prop3 x3 -> gemm1(+BN partials) -> ss.
// ---------------------------------------------------------------------------
__global__ __launch_bounds__(256, 2) void k_layer1(
        const float* __restrict__ x, const int* __restrict__ rowptr,
        const int* __restrict__ boff, const unsigned* __restrict__ edg,
        float* __restrict__ T3a, float* __restrict__ T3b, float* __restrict__ T3c,
        const float* __restrict__ W, const float* __restrict__ bias,
        float* __restrict__ out, float* __restrict__ gpart,
        const float* __restrict__ g1, const float* __restrict__ be1,
        float* __restrict__ ss, int* __restrict__ bar) {
    __shared__ float Ws[12 * 128];
    __shared__ float red[512];
    const int nblk = (int)gridDim.x;
    const int t = threadIdx.x;

    prop3_pass(x, nullptr, rowptr, boff, edg, T3a);
    gbar(bar, nblk, 1);
    prop3_pass(T3a, x, rowptr, boff, edg, T3b);
    gbar(bar, nblk, 2);
    prop3_pass(T3b, T3a, rowptr, boff, edg, T3c);
    gbar(bar, nblk, 3);

    // gemm1 (512 blocks x 98 rows) with fused BN partials
    for (int i = t; i < 12 * 128; i += 256) Ws[i] = W[i];
    __syncthreads();
    int f = t & 127;
    int half = t >> 7;
    float bs = bias[f];
    float bP = 0.f, bQ = 0.f;
    int r0 = blockIdx.x * 98;
    int r1 = r0 + 98;
    if (r1 > NN) r1 = NN;
    const float* Ts[4] = {x, T3a, T3b, T3c};
    for (int n = r0 + half; n < r1; n += 2) {
        float acc = bs;
        #pragma unroll
        for (int c = 0; c < 12; c++) {
            float tv = Ts[c / 3][n * 3 + (c % 3)];
            acc = fmaf(tv, Ws[c * 128 + f], acc);
        }
        acc = acc > 0.f ? acc : 0.01f * acc;
        out[n * HD + f] = acc;
        bP += acc;
        bQ += acc * acc;
    }
    red[t] = bP;
    red[256 + t] = bQ;
    __syncthreads();
    if (t < 128) {
        gpart[t * 512 + blockIdx.x] = red[t] + red[t + 128];
        gpart[(128 + t) * 512 + blockIdx.x] = red[256 + t] + red[256 + t + 128];
    }
    gbar(bar, nblk, 4);
    if (blockIdx.x == 0) ss_reduce(gpart, g1, be1, ss);
}

// ---------------------------------------------------------------------------
// dim-128 planar prop pass (device fn). XCD-pinned: blockIdx&7 constant under
// the g-stride (multiple of 8 blocks). Persistent grid = 768 (3 blocks/CU).
// ---------------------------------------------------------------------------
#define ACC8(acc, u, v)                                               \
    acc[0] = fmaf(v, __uint_as_float(u[0] << 16), acc[0]);            \
    acc[1] = fmaf(v, __uint_as_float(u[0] & 0xffff0000u), acc[1]);    \
    acc[2] = fmaf(v, __uint_as_float(u[1] << 16), acc[2]);            \
    acc[3] = fmaf(v, __uint_as_float(u[1] & 0xffff0000u), acc[3]);    \
    acc[4] = fmaf(v, __uint_as_float(u[2] << 16), acc[4]);            \
    acc[5] = fmaf(v, __uint_as_float(u[2] & 0xffff0000u), acc[5]);    \
    acc[6] = fmaf(v, __uint_as_float(u[3] << 16), acc[6]);            \
    acc[7] = fmaf(v, __uint_as_float(u[3] & 0xffff0000u), acc[7]);

__device__ void prop_pass(const unsigned short* __restrict__ h,
                          const unsigned short* __restrict__ sub,
                          const int* __restrict__ rowptr, const int* __restrict__ boff,
                          const unsigned* __restrict__ edg,
                          unsigned short* __restrict__ out) {
    const int tid = threadIdx.x;
    int xcd = blockIdx.x & 7;
    int c = xcd >> 1;
    int half = xcd & 1;
    int lane4 = tid & 3;
    int sl = lane4 * 8;
    int base = (tid & 63) & ~3;
    const unsigned short* hp = h + (size_t)c * (NN * 32);
    for (int g = blockIdx.x >> 3; g < 392; g += 96) {
        int n = (half * 392 + g) * 64 + (tid >> 2);
        if (n >= NN) continue;
        int e0 = rowptr[n] + boff[n >> 8];
        int e1 = rowptr[n + 1] + boff[(n + 1) >> 8];
        float a[8] = {0, 0, 0, 0, 0, 0, 0, 0};
        float b[8] = {0, 0, 0, 0, 0, 0, 0, 0};
        int e = e0;
        for (; e + 8 <= e1; e += 8) {
            uint2 pp = *(const uint2*)(edg + e + lane4 * 2);
            unsigned q0 = __shfl(pp.x, base + 0, 64);
            unsigned q1 = __shfl(pp.y, base + 0, 64);
            unsigned q2 = __shfl(pp.x, base + 1, 64);
            unsigned q3 = __shfl(pp.y, base + 1, 64);
            unsigned q4 = __shfl(pp.x, base + 2, 64);
            unsigned q5 = __shfl(pp.y, base + 2, 64);
            unsigned q6 = __shfl(pp.x, base + 3, 64);
            unsigned q7 = __shfl(pp.y, base + 3, 64);
            u32x4 u0 = *(const u32x4*)(hp + (q0 & 0xffffu) * 32 + sl);
            u32x4 u1 = *(const u32x4*)(hp + (q1 & 0xffffu) * 32 + sl);
            u32x4 u2 = *(const u32x4*)(hp + (q2 & 0xffffu) * 32 + sl);
            u32x4 u3 = *(const u32x4*)(hp + (q3 & 0xffffu) * 32 + sl);
            u32x4 u4 = *(const u32x4*)(hp + (q4 & 0xffffu) * 32 + sl);
            u32x4 u5 = *(const u32x4*)(hp + (q5 & 0xffffu) * 32 + sl);
            u32x4 u6 = *(const u32x4*)(hp + (q6 & 0xffffu) * 32 + sl);
            u32x4 u7 = *(const u32x4*)(hp + (q7 & 0xffffu) * 32 + sl);
            float v0 = edgw(q0), v1 = edgw(q1), v2 = edgw(q2), v3 = edgw(q3);
            float v4 = edgw(q4), v5 = edgw(q5), v6 = edgw(q6), v7 = edgw(q7);
            ACC8(a, u0, v0)
            ACC8(b, u1, v1)
            ACC8(a, u2, v2)
            ACC8(b, u3, v3)
            ACC8(a, u4, v4)
            ACC8(b, u5, v5)
            ACC8(a, u6, v6)
            ACC8(b, u7, v7)
        }
        int rem = e1 - e;
        if (rem > 0) {  // masked 8-wide tail; edg padded by 8 words
            uint2 pp = *(const uint2*)(edg + e + lane4 * 2);
            unsigned q0 = __shfl(pp.x, base + 0, 64);
            unsigned q1 = __shfl(pp.y, base + 0, 64);
            unsigned q2 = __shfl(pp.x, base + 1, 64);
            unsigned q3 = __shfl(pp.y, base + 1, 64);
            unsigned q4 = __shfl(pp.x, base + 2, 64);
            unsigned q5 = __shfl(pp.y, base + 2, 64);
            unsigned q6 = __shfl(pp.x, base + 3, 64);
            unsigned q7 = __shfl(pp.y, base + 3, 64);
            q1 = (rem > 1) ? q1 : 0u;
            q2 = (rem > 2) ? q2 : 0u;
            q3 = (rem > 3) ? q3 : 0u;
            q4 = (rem > 4) ? q4 : 0u;
            q5 = (rem > 5) ? q5 : 0u;
            q6 = (rem > 6) ? q6 : 0u;
            q7 = 0u;
            u32x4 u0 = *(const u32x4*)(hp + (q0 & 0xffffu) * 32 + sl);
            u32x4 u1 = *(const u32x4*)(hp + (q1 & 0xffffu) * 32 + sl);
            u32x4 u2 = *(const u32x4*)(hp + (q2 & 0xffffu) * 32 + sl);
            u32x4 u3 = *(const u32x4*)(hp + (q3 & 0xffffu) * 32 + sl);
            u32x4 u4 = *(const u32x4*)(hp + (q4 & 0xffffu) * 32 + sl);
            u32x4 u5 = *(const u32x4*)(hp + (q5 & 0xffffu) * 32 + sl);
            u32x4 u6 = *(const u32x4*)(hp + (q6 & 0xffffu) * 32 + sl);
            u32x4 u7 = *(const u32x4*)(hp + (q7 & 0xffffu) * 32 + sl);
            float v0 = edgw(q0), v1 = edgw(q1), v2 = edgw(q2), v3 = edgw(q3);
            float v4 = edgw(q4), v5 = edgw(q5), v6 = edgw(q6), v7 = edgw(q7);
            ACC8(a, u0, v0)
            ACC8(b, u1, v1)
            ACC8(a, u2, v2)
            ACC8(b, u3, v3)
            ACC8(a, u4, v4)
            ACC8(b, u5, v5)
            ACC8(a, u6, v6)
            ACC8(b, u7, v7)
        }
        float r[8];
        #pragma unroll
        for (int q = 0; q < 8; q++) r[q] = a[q] + b[q];
        if (sub) {
            u32x4 su = __builtin_nontemporal_load(
                (const u32x4*)(sub + (size_t)c * (NN * 32) + n * 32 + sl));
            float s[8];
            s[0] = __uint_as_float(su[0] << 16); s[1] = __uint_as_float(su[0] & 0xffff0000u);
            s[2] = __uint_as_float(su[1] << 16); s[3] = __uint_as_float(su[1] & 0xffff0000u);
            s[4] = __uint_as_float(su[2] << 16); s[5] = __uint_as_float(su[2] & 0xffff0000u);
            s[6] = __uint_as_float(su[3] << 16); s[7] = __uint_as_float(su[3] & 0xffff0000u);
            #pragma unroll
            for (int q = 0; q < 8; q++) r[q] = 2.f * r[q] - s[q];
        }
        u32x4 o;
        o[0] = bf2pack(r[0], r[1]);
        o[1] = bf2pack(r[2], r[3]);
        o[2] = bf2pack(r[4], r[5]);
        o[3] = bf2pack(r[6], r[7]);
        __builtin_nontemporal_store(o, (u32x4*)(out + (size_t)c * (NN * 32) + n * 32 + sl));
    }
}

// ---------------------------------------------------------------------------
// PROP BLOCK (persistent, 768 blocks): bncvt(F0,ss->Bb0) -> prop x3.
// pb = phase base (0 / 3 / 6 for the three launches sharing one bar slot).
// ---------------------------------------------------------------------------
__global__ __launch_bounds__(256, 3) void k_propB(
        const float* __restrict__ F0, const float* __restrict__ ss,
        unsigned short* __restrict__ Bb0, unsigned short* __restrict__ Bb1,
        unsigned short* __restrict__ Bb2, unsigned short* __restrict__ Bb3,
        const int* __restrict__ rowptr, const int* __restrict__ boff,
        const unsigned* __restrict__ edg, int* __restrict__ bar, int pb) {
    const int nblk = (int)gridDim.x;
    // P0: BN apply + fp32 -> bf16 feature-planar convert
    for (int idx = blockIdx.x * 256 + threadIdx.x; idx < NN * 16; idx += 768 * 256) {
        int n = idx >> 4;
        int p = (idx >> 2) & 3;
        int q = idx & 3;
        const float4* hf = (const float4*)F0;
        float4 v0 = hf[n * 32 + p * 8 + q * 2];
        float4 v1 = hf[n * 32 + p * 8 + q * 2 + 1];
        const float4* s4 = (const float4*)ss;
        float4 c0 = s4[p * 8 + q * 2];
        float4 c1 = s4[p * 8 + q * 2 + 1];
        float4 d0 = s4[32 + p * 8 + q * 2];
        float4 d1 = s4[32 + p * 8 + q * 2 + 1];
        v0.x = fmaf(v0.x, c0.x, d0.x); v0.y = fmaf(v0.y, c0.y, d0.y);
        v0.z = fmaf(v0.z, c0.z, d0.z); v0.w = fmaf(v0.w, c0.w, d0.w);
        v1.x = fmaf(v1.x, c1.x, d1.x); v1.y = fmaf(v1.y, c1.y, d1.y);
        v1.z = fmaf(v1.z, c1.z, d1.z); v1.w = fmaf(v1.w, c1.w, d1.w);
        uint4 o;
        o.x = bf2pack(v0.x, v0.y);
        o.y = bf2pack(v0.z, v0.w);
        o.z = bf2pack(v1.x, v1.y);
        o.w = bf2pack(v1.z, v1.w);
        ((uint4*)Bb0)[(size_t)p * (NN * 4) + n * 4 + q] = o;
    }
    gbar(bar, nblk, pb + 1);
    prop_pass(Bb0, nullptr, rowptr, boff, edg, Bb1);
    gbar(bar, nblk, pb + 2);
    prop_pass(Bb1, Bb0, rowptr, boff, edg, Bb2);
    gbar(bar, nblk, pb + 3);
    prop_pass(Bb2, Bb1, rowptr, boff, edg, Bb3);
}

// ---------------------------------------------------------------------------
// MFMA GEMM (512 blocks). act: 1=leaky, 2=relu, 3=none+fused row-L2-norm
// (final output). If gpart: fused BN partials -> barrier -> block0 ss.
// ---------------------------------------------------------------------------
__global__ __launch_bounds__(256, 2) void k_gemmL(
        const unsigned short* __restrict__ A0, const unsigned short* __restrict__ A1,
        const unsigned short* __restrict__ A2, const unsigned short* __restrict__ A3,
        const unsigned short* __restrict__ Wb, const float* __restrict__ bias,
        float* __restrict__ outF, int act, float* __restrict__ gpart,
        const float* __restrict__ gg, const float* __restrict__ be,
        float* __restrict__ ss, int* __restrict__ bar, int pb) {
    __shared__ unsigned short Asm[16 * 64 * 8];  // 16 KB
    __shared__ float sred[64];
    const int tid = threadIdx.x;
    const int w = tid >> 6;
    const int lane = tid & 63;
    const int l15 = lane & 15;
    const int quad = lane >> 4;

    short8 Bf[16][2];
    #pragma unroll
    for (int t = 0; t < 16; t++) {
        #pragma unroll
        for (int g = 0; g < 2; g++) {
            int slot = (w * 2 + g) * 16 + t;
            Bf[t][g] = *(const short8*)(Wb + slot * 512 + lane * 8);
        }
    }
    float bcol[2];
    bcol[0] = bias[w * 32 + l15];
    bcol[1] = bias[w * 32 + 16 + l15];

    const unsigned short* Ap[4] = {A0, A1, A2, A3};
    float bnP[2] = {0.f, 0.f}, bnQ[2] = {0.f, 0.f};

    for (int tile = blockIdx.x; tile < NN / 16; tile += gridDim.x) {
        int r0 = tile * 16;
        __syncthreads();
        #pragma unroll
        for (int i = 0; i < 4; i++) {
            int idx = i * 256 + tid;
            int s = idx >> 6;
            int ln = idx & 63;
            const unsigned short* src = Ap[s >> 2] + (size_t)(s & 3) * (NN * 32)
                                        + (r0 + (ln & 15)) * 32 + (ln >> 4) * 8;
            *(uint4*)&Asm[idx * 8] = *(const uint4*)src;
        }
        __syncthreads();
        f32x4 acc0 = {0.f, 0.f, 0.f, 0.f};
        f32x4 acc1 = {0.f, 0.f, 0.f, 0.f};
        #pragma unroll
        for (int s = 0; s < 16; s++) {
            short8 af = *(const short8*)&Asm[(s * 64 + lane) * 8];
            acc0 = __builtin_amdgcn_mfma_f32_16x16x32_bf16(af, Bf[s][0], acc0, 0, 0, 0);
            acc1 = __builtin_amdgcn_mfma_f32_16x16x32_bf16(af, Bf[s][1], acc1, 0, 0, 0);
        }
        if (act == 3) {
            float vv0[4], vv1[4], rs[4];
            #pragma unroll
            for (int reg = 0; reg < 4; reg++) {
                float v0 = acc0[reg] + bcol[0];
                float v1 = acc1[reg] + bcol[1];
                vv0[reg] = v0; vv1[reg] = v1;
                float s2 = v0 * v0 + v1 * v1;
                s2 += __shfl_xor(s2, 1);
                s2 += __shfl_xor(s2, 2);
                s2 += __shfl_xor(s2, 4);
                s2 += __shfl_xor(s2, 8);
                rs[reg] = s2;
            }
            if (l15 == 0) {
                #pragma unroll
                for (int reg = 0; reg < 4; reg++)
                    sred[w * 16 + quad * 4 + reg] = rs[reg];
            }
            __syncthreads();
            #pragma unroll
            for (int reg = 0; reg < 4; reg++) {
                int row16 = quad * 4 + reg;
                float tot = sred[row16] + sred[16 + row16]
                          + sred[32 + row16] + sred[48 + row16];
                float sc = 1.f / fmaxf(sqrtf(tot), 1e-12f);
                int row = r0 + row16;
                outF[row * HD + w * 32 + l15] = vv0[reg] * sc;
                outF[row * HD + w * 32 + 16 + l15] = vv1[reg] * sc;
            }
        } else {
            #pragma unroll
            for (int reg = 0; reg < 4; reg++) {
                int row = r0 + quad * 4 + reg;
                float v0 = acc0[reg] + bcol[0];
                float v1 = acc1[reg] + bcol[1];
                if (act == 1) {
                    v0 = v0 > 0.f ? v0 : 0.01f * v0;
                    v1 = v1 > 0.f ? v1 : 0.01f * v1;
                } else if (act == 2) {
                    v0 = v0 > 0.f ? v0 : 0.f;
                    v1 = v1 > 0.f ? v1 : 0.f;
                }
                outF[row * HD + w * 32 + l15] = v0;
                outF[row * HD + w * 32 + 16 + l15] = v1;
                bnP[0] += v0; bnQ[0] += v0 * v0;
                bnP[1] += v1; bnQ[1] += v1 * v1;
            }
        }
    }
    if (gpart) {
        #pragma unroll
        for (int g = 0; g < 2; g++) {
            float p = bnP[g], q = bnQ[g];
            p += __shfl_xor(p, 16); p += __shfl_xor(p, 32);
            q += __shfl_xor(q, 16); q += __shfl_xor(q, 32);
            if (quad == 0) {
                int col = w * 32 + g * 16 + l15;
                gpart[col * 512 + blockIdx.x] = p;
                gpart[(128 + col) * 512 + blockIdx.x] = q;
            }
        }
        gbar(bar, (int)gridDim.x, pb + 1);
        if (blockIdx.x == 0) ss_reduce(gpart, gg, be, ss);
    }
}

// ---------------------------------------------------------------------------
// Launch: 1 memset + 8 kernels (was 28 dispatches)
// ---------------------------------------------------------------------------
extern "C" void kernel_launch(void* const* d_in, const int* in_sizes, int n_in,
                              void* d_out, int out_size, void* d_ws, size_t ws_size,
                              hipStream_t stream) {
    const float* x  = (const float*)d_in[0];
    const int*   ei = (const int*)d_in[1];
    const float* W1 = (const float*)d_in[2];
    const float* b1 = (const float*)d_in[3];
    const float* W2 = (const float*)d_in[4];
    const float* b2 = (const float*)d_in[5];
    const float* W3 = (const float*)d_in[6];
    const float* b3 = (const float*)d_in[7];
    const float* W4 = (const float*)d_in[8];
    const float* b4 = (const float*)d_in[9];
    const float* g1 = (const float*)d_in[10];
    const float* be1 = (const float*)d_in[11];
    const float* g2 = (const float*)d_in[12];
    const float* be2 = (const float*)d_in[13];
    const float* g3 = (const float*)d_in[14];
    const float* be3 = (const float*)d_in[15];
    float* outp = (float*)d_out;

    char* base = (char*)d_ws;
    size_t off = 0;
    auto alloc = [&](size_t bytes) -> void* {
        void* p = base + off;
        off += (bytes + 255) & ~(size_t)255;
        return p;
    };
    float* dinv  = (float*)alloc(NN * 4);
    int*   cnt   = (int*)  alloc(NN * 4);
    int*   rowptr= (int*)  alloc((NN + 1) * 4);
    int*   bsum  = (int*)  alloc(256 * 4);
    int*   boff  = (int*)  alloc(256 * 4);
    int*   bar   = (int*)  alloc(64 * 4);
    float* ss    = (float*)alloc(256 * 4);
    float* gpart = (float*)alloc(256 * 512 * 4);
    unsigned short* Wb = (unsigned short*)alloc(3 * 512 * 128 * 2);
    unsigned* edg = (unsigned*)alloc((size_t)(NE + 8) * 4);  // +8 pad for masked tail
    float* T3a   = (float*)alloc(NN * 3 * 4);
    float* T3b   = (float*)alloc(NN * 3 * 4);
    float* T3c   = (float*)alloc(NN * 3 * 4);
    float* F0    = (float*)alloc((size_t)NN * HD * 4);
    unsigned short* Bb0 = (unsigned short*)alloc((size_t)NN * HD * 2);
    unsigned short* Bb1 = (unsigned short*)alloc((size_t)NN * HD * 2);
    unsigned short* Bb2 = (unsigned short*)alloc((size_t)NN * HD * 2);
    unsigned short* Bb3 = (unsigned short*)alloc((size_t)NN * HD * 2);

    // overlays (consumed before their host slabs are first written):
    unsigned* pre   = (unsigned*)F0;    // 12.8 MB, consumed in k_prep P4
    unsigned* phist = (unsigned*)Bb0;   // 25.6 MB (Bb0+Bb1 contiguous), consumed in P1

    unsigned short* Wb2 = Wb;
    unsigned short* Wb3 = Wb + 65536;
    unsigned short* Wb4 = Wb + 131072;

    hipMemsetAsync(bar, 0, 64 * sizeof(int), stream);

    k_prep<<<512, 256, 0, stream>>>(ei, dinv, cnt, rowptr, bsum, boff, pre, edg,
                                    W2, W3, W4, Wb, phist, bar + 0);
    k_layer1<<<512, 256, 0, stream>>>(x, rowptr, boff, edg, T3a, T3b, T3c,
                                      W1, b1, F0, gpart, g1, be1, ss, bar + 2);
    k_propB<<<768, 256, 0, stream>>>(F0, ss, Bb0, Bb1, Bb2, Bb3, rowptr, boff,
                                     edg, bar + 4, 0);
    k_gemmL<<<512, 256, 0, stream>>>(Bb0, Bb1, Bb2, Bb3, Wb2, b2, F0, 1, gpart,
                                     g2, be2, ss, bar + 6, 0);
    k_propB<<<768, 256, 0, stream>>>(F0, ss, Bb0, Bb1, Bb2, Bb3, rowptr, boff,
                                     edg, bar + 4, 3);
    k_gemmL<<<512, 256, 0, stream>>>(Bb0, Bb1, Bb2, Bb3, Wb3, b3, F0, 2, gpart,
                                     g3, be3, ss, bar + 6, 1);
    k_propB<<<768, 256, 0, stream>>>(F0, ss, Bb0, Bb1, Bb2, Bb3, rowptr, boff,
                                     edg, bar + 4, 6);
    k_gemmL<<<512, 256, 0, stream>>>(Bb0, Bb1, Bb2, Bb3, Wb4, b4, outp, 3, nullptr,
                                     nullptr, nullptr, nullptr, bar + 6, 2);

    (void)n_in; (void)in_sizes; (void)out_size; (void)ws_size;
}

// Round 6
// 626.265 us; speedup vs baseline: 4.0840x; 4.0840x over previous
//
#include <hip/hip_runtime.h>
#include <hip/hip_fp16.h>

#define NN 50000
#define NE 800000
#define HD 128
#define NSL 128          // edge slices
#define SLE (NE / NSL)   // 6250 edges per slice
#define PW  12500        // packed words per chunk (2 bins/word, 25000 bins/chunk)

typedef __attribute__((ext_vector_type(8))) short short8;
typedef __attribute__((ext_vector_type(4))) float f32x4;
typedef __attribute__((ext_vector_type(4))) unsigned u32x4;
typedef __attribute__((ext_vector_type(2))) unsigned u32x2;

__device__ inline unsigned bf2pack(float lo, float hi) {
    unsigned a = __float_as_uint(lo); a = (a + 0x7fffu + ((a >> 16) & 1u)) >> 16;
    unsigned b = __float_as_uint(hi); b = (b + 0x7fffu + ((b >> 16) & 1u)) >> 16;
    return a | (b << 16);
}

// packed edge: low 16 = src node, high 16 = fp16 weight
__device__ inline float edgw(unsigned p) {
    return __half2float(__ushort_as_half((unsigned short)(p >> 16)));
}

// ---------------------------------------------------------------------------
// Graph prep (atomic-free)
// ---------------------------------------------------------------------------
__global__ __launch_bounds__(256) void k_hist(const int* __restrict__ ei,
                                              unsigned* __restrict__ phist) {
    __shared__ unsigned hist[PW];  // 50 KB
    int b = blockIdx.x;
    int a = b >> 8;
    int s = (b & 255) >> 1;
    int c = b & 1;
    int tid = threadIdx.x;
    for (int i = tid; i < PW; i += 256) hist[i] = 0u;
    __syncthreads();
    const int* arr = ei + a * NE + s * SLE;
    int lo = c * 25000;
    for (int i = tid; i < SLE; i += 256) {
        int v = arr[i] - lo;
        if ((unsigned)v < 25000u)
            atomicAdd(&hist[v >> 1], 1u << ((v & 1) * 16));
    }
    __syncthreads();
    unsigned* dst = phist + (size_t)b * PW;
    for (int i = tid; i < PW; i += 256) dst[i] = hist[i];
}

__global__ __launch_bounds__(256) void k_hreduce(const unsigned* __restrict__ phist,
                                                 float* __restrict__ dinv,
                                                 int* __restrict__ cnt,
                                                 unsigned* __restrict__ pre) {
    int idx = blockIdx.x * 256 + threadIdx.x;
    if (idx >= 50000) return;
    int a = idx / 25000;
    int gw = idx % 25000;
    int c = gw / PW;
    int w = gw % PW;
    unsigned accLo = 0, accHi = 0;
    for (int s = 0; s < NSL; s++) {
        unsigned p = phist[(size_t)(((a * NSL + s) * 2 + c)) * PW + w];
        if (a == 1) pre[(size_t)s * 25000 + gw] = accLo | (accHi << 16);
        accLo += p & 0xffffu;
        accHi += p >> 16;
    }
    int b0 = c * 25000 + 2 * w;
    if (a == 0) {
        dinv[b0]     = accLo ? rsqrtf((float)accLo) : 0.0f;
        dinv[b0 + 1] = accHi ? rsqrtf((float)accHi) : 0.0f;
    } else {
        cnt[b0]     = (int)accLo;
        cnt[b0 + 1] = (int)accHi;
    }
}

__global__ __launch_bounds__(1024) void k_scan1(const int* __restrict__ cnt,
                                                int* __restrict__ rowptr,
                                                int* __restrict__ bsum) {
    __shared__ int s[1024];
    int tid = threadIdx.x;
    int gid = blockIdx.x * 1024 + tid;
    int v = (gid < NN) ? cnt[gid] : 0;
    s[tid] = v;
    __syncthreads();
    for (int off = 1; off < 1024; off <<= 1) {
        int t = 0;
        if (tid >= off) t = s[tid - off];
        __syncthreads();
        s[tid] += t;
        __syncthreads();
    }
    if (gid < NN) rowptr[gid] = s[tid] - v;
    if (tid == 1023) bsum[blockIdx.x] = s[1023];
}

// wave-parallel 64-element exclusive scan
__global__ void k_scan2(const int* __restrict__ bsum, int* __restrict__ boff,
                        int nb, int* __restrict__ rowptr) {
    int lane = threadIdx.x;  // 64 threads, one wave
    int v = (lane < nb) ? bsum[lane] : 0;
    int s = v;
    #pragma unroll
    for (int off = 1; off < 64; off <<= 1) {
        int t = __shfl_up(s, off, 64);
        if (lane >= off) s += t;
    }
    if (lane < nb) boff[lane] = s - v;
    if (lane == 63) rowptr[NN] = s;
}

__global__ void k_scan3(int* __restrict__ rowptr, const int* __restrict__ boff) {
    int i = blockIdx.x * 256 + threadIdx.x;
    if (i < NN) rowptr[i] += boff[i >> 10];
}

__global__ __launch_bounds__(256) void k_fill2(const int* __restrict__ ei,
                                               const float* __restrict__ dinv,
                                               const int* __restrict__ rowptr,
                                               const unsigned* __restrict__ pre,
                                               unsigned* __restrict__ edg) {
    __shared__ unsigned rank[PW];  // 50 KB
    int b = blockIdx.x;
    int s = b >> 1;
    int c = b & 1;
    int tid = threadIdx.x;
    for (int i = tid; i < PW; i += 256) rank[i] = 0u;
    __syncthreads();
    int lo = c * 25000;
    const unsigned* preS = pre + (size_t)s * 25000 + c * PW;
    for (int i = tid; i < SLE; i += 256) {
        int e = s * SLE + i;
        int d = ei[NE + e];
        int v = d - lo;
        if ((unsigned)v < 25000u) {
            int src = ei[e];
            int w = v >> 1;
            int sh = (v & 1) * 16;
            unsigned r = atomicAdd(&rank[w], 1u << sh);
            r = (r >> sh) & 0xffffu;
            unsigned pw = (preS[w] >> sh) & 0xffffu;
            int pos = rowptr[d] + (int)pw + (int)r;
            unsigned short hw = __half_as_ushort(__float2half(-dinv[src] * dinv[d]));
            edg[pos] = (unsigned)src | ((unsigned)hw << 16);
        }
    }
}

// ---------------------------------------------------------------------------
// Propagation dim-3 (fp32, layer 1 only). 4-edge unroll + masked tail.
// ---------------------------------------------------------------------------
__global__ __launch_bounds__(128) void k_prop3(const float* __restrict__ h,
                        const float* __restrict__ sub,
                        const int* __restrict__ rowptr, const unsigned* __restrict__ edg,
                        float* __restrict__ out) {
    int node = blockIdx.x * 128 + threadIdx.x;
    if (node >= NN) return;
    int e0 = rowptr[node], e1 = rowptr[node + 1];
    float a0 = 0.f, a1 = 0.f, a2 = 0.f;
    float c0 = 0.f, c1 = 0.f, c2 = 0.f;
    int e = e0;
    for (; e + 4 <= e1; e += 4) {
        unsigned p0 = edg[e], p1 = edg[e + 1], p2 = edg[e + 2], p3 = edg[e + 3];
        int s0 = (int)(p0 & 0xffffu) * 3, s1 = (int)(p1 & 0xffffu) * 3;
        int s2 = (int)(p2 & 0xffffu) * 3, s3 = (int)(p3 & 0xffffu) * 3;
        float x0 = h[s0], y0 = h[s0 + 1], z0 = h[s0 + 2];
        float x1 = h[s1], y1 = h[s1 + 1], z1 = h[s1 + 2];
        float x2 = h[s2], y2 = h[s2 + 1], z2 = h[s2 + 2];
        float x3 = h[s3], y3 = h[s3 + 1], z3 = h[s3 + 2];
        float w0 = edgw(p0), w1 = edgw(p1), w2 = edgw(p2), w3 = edgw(p3);
        a0 = fmaf(w0, x0, a0); a1 = fmaf(w0, y0, a1); a2 = fmaf(w0, z0, a2);
        c0 = fmaf(w1, x1, c0); c1 = fmaf(w1, y1, c1); c2 = fmaf(w1, z1, c2);
        a0 = fmaf(w2, x2, a0); a1 = fmaf(w2, y2, a1); a2 = fmaf(w2, z2, a2);
        c0 = fmaf(w3, x3, c0); c1 = fmaf(w3, y3, c1); c2 = fmaf(w3, z3, c2);
    }
    if (e < e1) {  // masked 3-wide tail: packed 0 -> src 0, weight 0.0 (exact no-op)
        unsigned p0 = edg[e];
        unsigned p1 = (e + 1 < e1) ? edg[e + 1] : 0u;
        unsigned p2 = (e + 2 < e1) ? edg[e + 2] : 0u;
        int s0 = (int)(p0 & 0xffffu) * 3, s1 = (int)(p1 & 0xffffu) * 3;
        int s2 = (int)(p2 & 0xffffu) * 3;
        float x0 = h[s0], y0 = h[s0 + 1], z0 = h[s0 + 2];
        float x1 = h[s1], y1 = h[s1 + 1], z1 = h[s1 + 2];
        float x2 = h[s2], y2 = h[s2 + 1], z2 = h[s2 + 2];
        float w0 = edgw(p0), w1 = edgw(p1), w2 = edgw(p2);
        a0 = fmaf(w0, x0, a0); a1 = fmaf(w0, y0, a1); a2 = fmaf(w0, z0, a2);
        c0 = fmaf(w1, x1, c0); c1 = fmaf(w1, y1, c1); c2 = fmaf(w1, z1, c2);
        a0 = fmaf(w2, x2, a0); a1 = fmaf(w2, y2, a1); a2 = fmaf(w2, z2, a2);
    }
    a0 += c0; a1 += c1; a2 += c2;
    if (sub) {
        a0 = 2.f * a0 - sub[node * 3 + 0];
        a1 = 2.f * a1 - sub[node * 3 + 1];
        a2 = 2.f * a2 - sub[node * 3 + 2];
    }
    out[node * 3 + 0] = a0;
    out[node * 3 + 1] = a1;
    out[node * 3 + 2] = a2;
}

// ---------------------------------------------------------------------------
// Propagation dim-128, feature-planar bf16 [plane 0..3][node][32].
// XCD-pinned chunks; 8-edge unroll. (a) edge u32x2 loads NON-TEMPORAL
// (streamed once/pass/XCD; keeps 3.2 MB h-plane L2-resident), (b) edge load
// SOFTWARE-PIPELINED one iteration ahead (removes ~200-300 cy of edge-load
// latency from every iteration's serial chain). +8-word edg pad bounds all
// prefetch over-reads; tail consumes the prefetched value (bit-identical).
// ---------------------------------------------------------------------------
#define ACC8(acc, u, v)                                               \
    acc[0] = fmaf(v, __uint_as_float(u[0] << 16), acc[0]);            \
    acc[1] = fmaf(v, __uint_as_float(u[0] & 0xffff0000u), acc[1]);    \
    acc[2] = fmaf(v, __uint_as_float(u[1] << 16), acc[2]);            \
    acc[3] = fmaf(v, __uint_as_float(u[1] & 0xffff0000u), acc[3]);    \
    acc[4] = fmaf(v, __uint_as_float(u[2] << 16), acc[4]);            \
    acc[5] = fmaf(v, __uint_as_float(u[2] & 0xffff0000u), acc[5]);    \
    acc[6] = fmaf(v, __uint_as_float(u[3] << 16), acc[6]);            \
    acc[7] = fmaf(v, __uint_as_float(u[3] & 0xffff0000u), acc[7]);

__global__ __launch_bounds__(256) void k_prop_pl(
        const unsigned short* __restrict__ h, const unsigned short* __restrict__ sub,
        const int* __restrict__ rowptr, const unsigned* __restrict__ edg,
        unsigned short* __restrict__ out) {
    int B = blockIdx.x;
    int xcd = B & 7;
    int c = xcd >> 1;        // chunk pinned to XCD pair
    int half = xcd & 1;      // node-range half
    int g = B >> 3;          // 0..391
    int n = (half * 392 + g) * 64 + (threadIdx.x >> 2);
    if (n >= NN) return;
    int lane4 = threadIdx.x & 3;
    int sl = lane4 * 8;                       // ushort slice offset
    int base = (threadIdx.x & 63) & ~3;       // node's first lane in wave
    const unsigned short* hp = h + (size_t)c * (NN * 32);
    int e0 = rowptr[n], e1 = rowptr[n + 1];
    float a[8] = {0, 0, 0, 0, 0, 0, 0, 0};
    float b[8] = {0, 0, 0, 0, 0, 0, 0, 0};
    int e = e0;
    // prefetch first 8-edge packet (pad-bounded; unused if row empty)
    u32x2 pp = __builtin_nontemporal_load((const u32x2*)(edg + e + lane4 * 2));
    for (; e + 8 <= e1; e += 8) {
        u32x2 cur = pp;
        pp = __builtin_nontemporal_load((const u32x2*)(edg + e + 8 + lane4 * 2));
        unsigned q0 = __shfl(cur[0], base + 0, 64);
        unsigned q1 = __shfl(cur[1], base + 0, 64);
        unsigned q2 = __shfl(cur[0], base + 1, 64);
        unsigned q3 = __shfl(cur[1], base + 1, 64);
        unsigned q4 = __shfl(cur[0], base + 2, 64);
        unsigned q5 = __shfl(cur[1], base + 2, 64);
        unsigned q6 = __shfl(cur[0], base + 3, 64);
        unsigned q7 = __shfl(cur[1], base + 3, 64);
        u32x4 u0 = *(const u32x4*)(hp + (q0 & 0xffffu) * 32 + sl);
        u32x4 u1 = *(const u32x4*)(hp + (q1 & 0xffffu) * 32 + sl);
        u32x4 u2 = *(const u32x4*)(hp + (q2 & 0xffffu) * 32 + sl);
        u32x4 u3 = *(const u32x4*)(hp + (q3 & 0xffffu) * 32 + sl);
        u32x4 u4 = *(const u32x4*)(hp + (q4 & 0xffffu) * 32 + sl);
        u32x4 u5 = *(const u32x4*)(hp + (q5 & 0xffffu) * 32 + sl);
        u32x4 u6 = *(const u32x4*)(hp + (q6 & 0xffffu) * 32 + sl);
        u32x4 u7 = *(const u32x4*)(hp + (q7 & 0xffffu) * 32 + sl);
        float v0 = edgw(q0), v1 = edgw(q1), v2 = edgw(q2), v3 = edgw(q3);
        float v4 = edgw(q4), v5 = edgw(q5), v6 = edgw(q6), v7 = edgw(q7);
        ACC8(a, u0, v0)
        ACC8(b, u1, v1)
        ACC8(a, u2, v2)
        ACC8(b, u3, v3)
        ACC8(a, u4, v4)
        ACC8(b, u5, v5)
        ACC8(a, u6, v6)
        ACC8(b, u7, v7)
    }
    int rem = e1 - e;        // 0..7
    if (rem > 0) {
        // pp already holds the tail packet (prefetched); sanitize beyond rem
        unsigned q0 = __shfl(pp[0], base + 0, 64);
        unsigned q1 = __shfl(pp[1], base + 0, 64);
        unsigned q2 = __shfl(pp[0], base + 1, 64);
        unsigned q3 = __shfl(pp[1], base + 1, 64);
        unsigned q4 = __shfl(pp[0], base + 2, 64);
        unsigned q5 = __shfl(pp[1], base + 2, 64);
        unsigned q6 = __shfl(pp[0], base + 3, 64);
        unsigned q7 = __shfl(pp[1], base + 3, 64);
        q1 = (rem > 1) ? q1 : 0u;
        q2 = (rem > 2) ? q2 : 0u;
        q3 = (rem > 3) ? q3 : 0u;
        q4 = (rem > 4) ? q4 : 0u;
        q5 = (rem > 5) ? q5 : 0u;
        q6 = (rem > 6) ? q6 : 0u;
        q7 = 0u;
        u32x4 u0 = *(const u32x4*)(hp + (q0 & 0xffffu) * 32 + sl);
        u32x4 u1 = *(const u32x4*)(hp + (q1 & 0xffffu) * 32 + sl);
        u32x4 u2 = *(const u32x4*)(hp + (q2 & 0xffffu) * 32 + sl);
        u32x4 u3 = *(const u32x4*)(hp + (q3 & 0xffffu) * 32 + sl);
        u32x4 u4 = *(const u32x4*)(hp + (q4 & 0xffffu) * 32 + sl);
        u32x4 u5 = *(const u32x4*)(hp + (q5 & 0xffffu) * 32 + sl);
        u32x4 u6 = *(const u32x4*)(hp + (q6 & 0xffffu) * 32 + sl);
        u32x4 u7 = *(const u32x4*)(hp + (q7 & 0xffffu) * 32 + sl);
        float v0 = edgw(q0), v1 = edgw(q1), v2 = edgw(q2), v3 = edgw(q3);
        float v4 = edgw(q4), v5 = edgw(q5), v6 = edgw(q6), v7 = edgw(q7);
        ACC8(a, u0, v0)
        ACC8(b, u1, v1)
        ACC8(a, u2, v2)
        ACC8(b, u3, v3)
        ACC8(a, u4, v4)
        ACC8(b, u5, v5)
        ACC8(a, u6, v6)
        ACC8(b, u7, v7)
    }
    float r[8];
    #pragma unroll
    for (int q = 0; q < 8; q++) r[q] = a[q] + b[q];
    if (sub) {
        u32x4 su = __builtin_nontemporal_load(
            (const u32x4*)(sub + (size_t)c * (NN * 32) + n * 32 + sl));
        float s[8];
        s[0] = __uint_as_float(su[0] << 16); s[1] = __uint_as_float(su[0] & 0xffff0000u);
        s[2] = __uint_as_float(su[1] << 16); s[3] = __uint_as_float(su[1] & 0xffff0000u);
        s[4] = __uint_as_float(su[2] << 16); s[5] = __uint_as_float(su[2] & 0xffff0000u);
        s[6] = __uint_as_float(su[3] << 16); s[7] = __uint_as_float(su[3] & 0xffff0000u);
        #pragma unroll
        for (int q = 0; q < 8; q++) r[q] = 2.f * r[q] - s[q];
    }
    u32x4 o;
    o[0] = bf2pack(r[0], r[1]);
    o[1] = bf2pack(r[2], r[3]);
    o[2] = bf2pack(r[4], r[5]);
    o[3] = bf2pack(r[6], r[7]);
    __builtin_nontemporal_store(o, (u32x4*)(out + (size_t)c * (NN * 32) + n * 32 + sl));
}

// ---------------------------------------------------------------------------
// W swizzle fp32 -> bf16 B-fragment order for all three 128x128 weights.
// ---------------------------------------------------------------------------
__global__ void k_wconv_all(const float* __restrict__ W2, const float* __restrict__ W3,
                            const float* __restrict__ W4, unsigned short* __restrict__ Wb) {
    int gidx = blockIdx.x * 256 + threadIdx.x;  // 0..196607
    int which = gidx >> 16;
    int idx = gidx & 65535;
    const float* W = which == 0 ? W2 : (which == 1 ? W3 : W4);
    int slot = idx >> 9;
    int lane = (idx >> 3) & 63;
    int j = idx & 7;
    int wg = slot >> 4;
    int t = slot & 15;
    int w = wg >> 1;
    int g = wg & 1;
    int k = t * 32 + (lane >> 4) * 8 + j;
    int col = w * 32 + g * 16 + (lane & 15);
    unsigned u = __float_as_uint(W[k * HD + col]);
    Wb[which * 65536 + idx] = (unsigned short)((u + 0x7fffu + ((u >> 16) & 1u)) >> 16);
}

// ---------------------------------------------------------------------------
// MFMA GEMM. A staged per 16-row tile into LDS (fragment order); B register-
// resident. act: 0=none, 1=leaky, 2=relu, 3=none+fused row-L2-normalize
// (layer 4: outF is the FINAL output). Fused BN partials -> gpart[col][512].
// ---------------------------------------------------------------------------
__global__ __launch_bounds__(256) void k_gemmM(
        const unsigned short* __restrict__ A0, const unsigned short* __restrict__ A1,
        const unsigned short* __restrict__ A2, const unsigned short* __restrict__ A3,
        const unsigned short* __restrict__ Wb, const float* __restrict__ bias,
        float* __restrict__ outF, int act, float* __restrict__ gpart) {
    __shared__ unsigned short Asm[16 * 64 * 8];  // 16 KB
    __shared__ float sred[64];                   // l2-mode cross-wave row sums
    const int tid = threadIdx.x;
    const int w = tid >> 6;
    const int lane = tid & 63;
    const int l15 = lane & 15;
    const int quad = lane >> 4;

    short8 Bf[16][2];
    #pragma unroll
    for (int t = 0; t < 16; t++) {
        #pragma unroll
        for (int g = 0; g < 2; g++) {
            int slot = (w * 2 + g) * 16 + t;
            Bf[t][g] = *(const short8*)(Wb + slot * 512 + lane * 8);
        }
    }
    float bcol[2];
    bcol[0] = bias[w * 32 + l15];
    bcol[1] = bias[w * 32 + 16 + l15];

    const unsigned short* Ap[4] = {A0, A1, A2, A3};
    float bnP[2] = {0.f, 0.f}, bnQ[2] = {0.f, 0.f};

    for (int tile = blockIdx.x; tile < NN / 16; tile += gridDim.x) {
        int r0 = tile * 16;
        __syncthreads();
        #pragma unroll
        for (int i = 0; i < 4; i++) {
            int idx = i * 256 + tid;          // 0..1023
            int s = idx >> 6;                 // frag slot 0..15
            int ln = idx & 63;
            const unsigned short* src = Ap[s >> 2] + (size_t)(s & 3) * (NN * 32)
                                        + (r0 + (ln & 15)) * 32 + (ln >> 4) * 8;
            *(uint4*)&Asm[idx * 8] = *(const uint4*)src;
        }
        __syncthreads();
        f32x4 acc0 = {0.f, 0.f, 0.f, 0.f};
        f32x4 acc1 = {0.f, 0.f, 0.f, 0.f};
        #pragma unroll
        for (int s = 0; s < 16; s++) {
            short8 af = *(const short8*)&Asm[(s * 64 + lane) * 8];
            acc0 = __builtin_amdgcn_mfma_f32_16x16x32_bf16(af, Bf[s][0], acc0, 0, 0, 0);
            acc1 = __builtin_amdgcn_mfma_f32_16x16x32_bf16(af, Bf[s][1], acc1, 0, 0, 0);
        }
        if (act == 3) {
            // ---- fused row L2 normalize; write final output ----
            float vv0[4], vv1[4], rs[4];
            #pragma unroll
            for (int reg = 0; reg < 4; reg++) {
                float v0 = acc0[reg] + bcol[0];
                float v1 = acc1[reg] + bcol[1];
                vv0[reg] = v0; vv1[reg] = v1;
                float s2 = v0 * v0 + v1 * v1;
                s2 += __shfl_xor(s2, 1);
                s2 += __shfl_xor(s2, 2);
                s2 += __shfl_xor(s2, 4);
                s2 += __shfl_xor(s2, 8);
                rs[reg] = s2;  // this wave's 32-col partial for row quad*4+reg
            }
            if (l15 == 0) {
                #pragma unroll
                for (int reg = 0; reg < 4; reg++)
                    sred[w * 16 + quad * 4 + reg] = rs[reg];
            }
            __syncthreads();
            #pragma unroll
            for (int reg = 0; reg < 4; reg++) {
                int row16 = quad * 4 + reg;
                float tot = sred[row16] + sred[16 + row16]
                          + sred[32 + row16] + sred[48 + row16];
                float sc = 1.f / fmaxf(sqrtf(tot), 1e-12f);
                int row = r0 + row16;
                outF[row * HD + w * 32 + l15] = vv0[reg] * sc;
                outF[row * HD + w * 32 + 16 + l15] = vv1[reg] * sc;
            }
        } else {
            #pragma unroll
            for (int reg = 0; reg < 4; reg++) {
                int row = r0 + quad * 4 + reg;
                float v0 = acc0[reg] + bcol[0];
                float v1 = acc1[reg] + bcol[1];
                if (act == 1) {
                    v0 = v0 > 0.f ? v0 : 0.01f * v0;
                    v1 = v1 > 0.f ? v1 : 0.01f * v1;
                } else if (act == 2) {
                    v0 = v0 > 0.f ? v0 : 0.f;
                    v1 = v1 > 0.f ? v1 : 0.f;
                }
                outF[row * HD + w * 32 + l15] = v0;
                outF[row * HD + w * 32 + 16 + l15] = v1;
                bnP[0] += v0; bnQ[0] += v0 * v0;
                bnP[1] += v1; bnQ[1] += v1 * v1;
            }
        }
    }
    if (gpart) {
        #pragma unroll
        for (int g = 0; g < 2; g++) {
            float p = bnP[g], q = bnQ[g];
            p += __shfl_xor(p, 16); p += __shfl_xor(p, 32);
            q += __shfl_xor(q, 16); q += __shfl_xor(q, 32);
            if (quad == 0) {
                int col = w * 32 + g * 16 + l15;
                gpart[col * 512 + blockIdx.x] = p;
                gpart[(128 + col) * 512 + blockIdx.x] = q;
            }
        }
    }
}

// ---------------------------------------------------------------------------
// Layer-1 GEMM: [N,3] x4 Cheb terms @ W1[4][3][128] + b, leaky relu -> fp32,
// with FUSED BN partial sums.
// ---------------------------------------------------------------------------
__global__ __launch_bounds__(256) void k_gemm1(
        const float* __restrict__ T0, const float* __restrict__ T1,
        const float* __restrict__ T2, const float* __restrict__ T3,
        const float* __restrict__ W, const float* __restrict__ bias,
        float* __restrict__ out, float* __restrict__ gpart) {
    __shared__ float Ws[12 * 128];
    __shared__ float red[512];
    int t = threadIdx.x;
    for (int i = t; i < 12 * 128; i += 256) Ws[i] = W[i];
    __syncthreads();
    int f = t & 127;
    int half = t >> 7;
    float bs = bias[f];
    float bP = 0.f, bQ = 0.f;
    int r0 = blockIdx.x * 98;
    int r1 = r0 + 98;
    if (r1 > NN) r1 = NN;
    const float* Ts[4] = {T0, T1, T2, T3};
    for (int n = r0 + half; n < r1; n += 2) {
        float acc = bs;
        #pragma unroll
        for (int c = 0; c < 12; c++) {
            float tv = Ts[c / 3][n * 3 + (c % 3)];
            acc = fmaf(tv, Ws[c * 128 + f], acc);
        }
        acc = acc > 0.f ? acc : 0.01f * acc;
        out[n * HD + f] = acc;
        bP += acc;
        bQ += acc * acc;
    }
    red[t] = bP;
    red[256 + t] = bQ;
    __syncthreads();
    if (t < 128) {
        gpart[t * 512 + blockIdx.x] = red[t] + red[t + 128];
        gpart[(128 + t) * 512 + blockIdx.x] = red[256 + t] + red[256 + t + 128];
    }
}

__global__ __launch_bounds__(128) void k_bnredfin(const float* __restrict__ gpart,
                                                  const float* __restrict__ g,
                                                  const float* __restrict__ be,
                                                  float* __restrict__ ss) {
    __shared__ float sm[2];
    int f = blockIdx.x;            // 0..127
    int wave = threadIdx.x >> 6;   // 0: sum, 1: sumsq
    int lane = threadIdx.x & 63;
    const float* src = gpart + (size_t)(f + wave * 128) * 512;
    float s = 0.f;
    #pragma unroll
    for (int i = 0; i < 8; i++) s += src[i * 64 + lane];
    #pragma unroll
    for (int off = 32; off > 0; off >>= 1) s += __shfl_xor(s, off);
    if (lane == 0) sm[wave] = s;
    __syncthreads();
    if (threadIdx.x == 0) {
        float mean = sm[0] * (1.0f / NN);
        float var = sm[1] * (1.0f / NN) - mean * mean;
        float sc = g[f] * rsqrtf(var + 1e-5f);
        ss[f] = sc;
        ss[128 + f] = be[f] - mean * sc;
    }
}

// BN apply on fp32 row-major src -> bf16 feature-planar out
__global__ void k_bncvt_pl(const float* __restrict__ h, const float* __restrict__ ss,
                           unsigned short* __restrict__ out) {
    int idx = blockIdx.x * 256 + threadIdx.x;  // over NN*16 chunks of 8 feats
    if (idx < NN * 16) {
        int n = idx >> 4;
        int p = (idx >> 2) & 3;
        int q = idx & 3;
        const float4* hf = (const float4*)h;
        float4 v0 = hf[n * 32 + p * 8 + q * 2];
        float4 v1 = hf[n * 32 + p * 8 + q * 2 + 1];
        const float4* s4 = (const float4*)ss;
        float4 c0 = s4[p * 8 + q * 2];
        float4 c1 = s4[p * 8 + q * 2 + 1];
        float4 d0 = s4[32 + p * 8 + q * 2];
        float4 d1 = s4[32 + p * 8 + q * 2 + 1];
        v0.x = fmaf(v0.x, c0.x, d0.x); v0.y = fmaf(v0.y, c0.y, d0.y);
        v0.z = fmaf(v0.z, c0.z, d0.z); v0.w = fmaf(v0.w, c0.w, d0.w);
        v1.x = fmaf(v1.x, c1.x, d1.x); v1.y = fmaf(v1.y, c1.y, d1.y);
        v1.z = fmaf(v1.z, c1.z, d1.z); v1.w = fmaf(v1.w, c1.w, d1.w);
        uint4 o;
        o.x = bf2pack(v0.x, v0.y);
        o.y = bf2pack(v0.z, v0.w);
        o.z = bf2pack(v1.x, v1.y);
        o.w = bf2pack(v1.z, v1.w);
        ((uint4*)out)[(size_t)p * (NN * 4) + n * 4 + q] = o;
    }
}

// ---------------------------------------------------------------------------
// Launch
// ---------------------------------------------------------------------------
extern "C" void kernel_launch(void* const* d_in, const int* in_sizes, int n_in,
                              void* d_out, int out_size, void* d_ws, size_t ws_size,
                              hipStream_t stream) {
    const float* x  = (const float*)d_in[0];
    const int*   ei = (const int*)d_in[1];
    const float* W1 = (const float*)d_in[2];
    const float* b1 = (const float*)d_in[3];
    const float* W2 = (const float*)d_in[4];
    const float* b2 = (const float*)d_in[5];
    const float* W3 = (const float*)d_in[6];
    const float* b3 = (const float*)d_in[7];
    const float* W4 = (const float*)d_in[8];
    const float* b4 = (const float*)d_in[9];
    const float* g1 = (const float*)d_in[10];
    const float* be1 = (const float*)d_in[11];
    const float* g2 = (const float*)d_in[12];
    const float* be2 = (const float*)d_in[13];
    const float* g3 = (const float*)d_in[14];
    const float* be3 = (const float*)d_in[15];
    float* outp = (float*)d_out;

    char* base = (char*)d_ws;
    size_t off = 0;
    auto alloc = [&](size_t bytes) -> void* {
        void* p = base + off;
        off += (bytes + 255) & ~(size_t)255;
        return p;
    };
    float* dinv  = (float*)alloc(NN * 4);
    int*   cnt   = (int*)  alloc(NN * 4);
    int*   rowptr= (int*)  alloc((NN + 1) * 4);
    int*   bsum  = (int*)  alloc(64 * 4);
    int*   boff  = (int*)  alloc(64 * 4);
    float* ss    = (float*)alloc(256 * 4);
    float* gpart = (float*)alloc(256 * 512 * 4);
    unsigned short* Wb = (unsigned short*)alloc(3 * 512 * 128 * 2);
    unsigned* edg = (unsigned*)alloc((size_t)(NE + 8) * 4);  // +8 pad for masked tail
    float* T3a   = (float*)alloc(NN * 3 * 4);
    float* T3b   = (float*)alloc(NN * 3 * 4);
    float* T3c   = (float*)alloc(NN * 3 * 4);
    float* F0    = (float*)alloc((size_t)NN * HD * 4);
    unsigned short* Bb0 = (unsigned short*)alloc((size_t)NN * HD * 2);
    unsigned short* Bb1 = (unsigned short*)alloc((size_t)NN * HD * 2);
    unsigned short* Bb2 = (unsigned short*)alloc((size_t)NN * HD * 2);
    unsigned short* Bb3 = (unsigned short*)alloc((size_t)NN * HD * 2);

    // overlays (consumed before their host slabs are first written):
    unsigned* pre   = (unsigned*)F0;    // 12.8 MB, freed by k_fill2
    unsigned* phist = (unsigned*)Bb0;   // 25.6 MB (Bb0+Bb1), freed by k_hreduce

    const int gN = (NN + 255) / 256;
    const int gP3 = (NN + 127) / 128;
    const int nb = (NN + 1023) / 1024;

    // ---- graph prep (no global atomics) ----
    k_hist<<<512, 256, 0, stream>>>(ei, phist);
    k_hreduce<<<(50000 + 255) / 256, 256, 0, stream>>>(phist, dinv, cnt, pre);
    k_scan1<<<nb, 1024, 0, stream>>>(cnt, rowptr, bsum);
    k_scan2<<<1, 64, 0, stream>>>(bsum, boff, nb, rowptr);
    k_scan3<<<gN, 256, 0, stream>>>(rowptr, boff);
    k_fill2<<<256, 256, 0, stream>>>(ei, dinv, rowptr, pre, edg);
    k_wconv_all<<<768, 256, 0, stream>>>(W2, W3, W4, Wb);

    const int gPP = 8 * 392;         // XCD-pinned planar prop
    const int gG = 512;              // gemmM grid-stride blocks
    const int gCvt = NN * 16 / 256;  // 3125
    unsigned short* Wb2 = Wb;
    unsigned short* Wb3 = Wb + 65536;
    unsigned short* Wb4 = Wb + 131072;

    // ---- layer 1 (in: x [N,3], fp32) ----
    k_prop3<<<gP3, 128, 0, stream>>>(x, nullptr, rowptr, edg, T3a);
    k_prop3<<<gP3, 128, 0, stream>>>(T3a, x, rowptr, edg, T3b);
    k_prop3<<<gP3, 128, 0, stream>>>(T3b, T3a, rowptr, edg, T3c);
    k_gemm1<<<512, 256, 0, stream>>>(x, T3a, T3b, T3c, W1, b1, F0, gpart);
    k_bnredfin<<<128, 128, 0, stream>>>(gpart, g1, be1, ss);
    k_bncvt_pl<<<gCvt, 256, 0, stream>>>(F0, ss, Bb0);

    // ---- layer 2 ----
    k_prop_pl<<<gPP, 256, 0, stream>>>(Bb0, nullptr, rowptr, edg, Bb1);
    k_prop_pl<<<gPP, 256, 0, stream>>>(Bb1, Bb0, rowptr, edg, Bb2);
    k_prop_pl<<<gPP, 256, 0, stream>>>(Bb2, Bb1, rowptr, edg, Bb3);
    k_gemmM<<<gG, 256, 0, stream>>>(Bb0, Bb1, Bb2, Bb3, Wb2, b2, F0, 1, gpart);
    k_bnredfin<<<128, 128, 0, stream>>>(gpart, g2, be2, ss);
    k_bncvt_pl<<<gCvt, 256, 0, stream>>>(F0, ss, Bb0);

    // ---- layer 3 ----
    k_prop_pl<<<gPP, 256, 0, stream>>>(Bb0, nullptr, rowptr, edg, Bb1);
    k_prop_pl<<<gPP, 256, 0, stream>>>(Bb1, Bb0, rowptr, edg, Bb2);
    k_prop_pl<<<gPP, 256, 0, stream>>>(Bb2, Bb1, rowptr, edg, Bb3);
    k_gemmM<<<gG, 256, 0, stream>>>(Bb0, Bb1, Bb2, Bb3, Wb3, b3, F0, 2, gpart);
    k_bnredfin<<<128, 128, 0, stream>>>(gpart, g3, be3, ss);
    k_bncvt_pl<<<gCvt, 256, 0, stream>>>(F0, ss, Bb0);

    // ---- layer 4 (GEMM + fused row-L2-normalize -> final output) ----
    k_prop_pl<<<gPP, 256, 0, stream>>>(Bb0, nullptr, rowptr, edg, Bb1);
    k_prop_pl<<<gPP, 256, 0, stream>>>(Bb1, Bb0, rowptr, edg, Bb2);
    k_prop_pl<<<gPP, 256, 0, stream>>>(Bb2, Bb1, rowptr, edg, Bb3);
    k_gemmM<<<gG, 256, 0, stream>>>(Bb0, Bb1, Bb2, Bb3, Wb4, b4, outp, 3, nullptr);

    (void)n_in; (void)in_sizes; (void)out_size; (void)ws_size;
}

// Round 7
// 535.189 us; speedup vs baseline: 4.7790x; 1.1702x over previous
//
#include <hip/hip_runtime.h>
#include <hip/hip_fp16.h>

#define NN 50000
#define NE 800000
#define HD 128
#define NSL 128          // edge slices
#define SLE (NE / NSL)   // 6250 edges per slice
#define PW  12500        // packed words per chunk (2 bins/word, 25000 bins/chunk)

typedef __attribute__((ext_vector_type(8))) short short8;
typedef __attribute__((ext_vector_type(4))) float f32x4;
typedef __attribute__((ext_vector_type(4))) unsigned u32x4;
typedef __attribute__((ext_vector_type(2))) unsigned u32x2;

__device__ inline unsigned bf2pack(float lo, float hi) {
    unsigned a = __float_as_uint(lo); a = (a + 0x7fffu + ((a >> 16) & 1u)) >> 16;
    unsigned b = __float_as_uint(hi); b = (b + 0x7fffu + ((b >> 16) & 1u)) >> 16;
    return a | (b << 16);
}

// packed edge: low 16 = src node, high 16 = fp16 weight
__device__ inline float edgw(unsigned p) {
    return __half2float(__ushort_as_half((unsigned short)(p >> 16)));
}

// ---------------------------------------------------------------------------
// Graph prep (atomic-free)
// ---------------------------------------------------------------------------
__global__ __launch_bounds__(256) void k_hist(const int* __restrict__ ei,
                                              unsigned* __restrict__ phist) {
    __shared__ unsigned hist[PW];  // 50 KB
    int b = blockIdx.x;
    int a = b >> 8;
    int s = (b & 255) >> 1;
    int c = b & 1;
    int tid = threadIdx.x;
    for (int i = tid; i < PW; i += 256) hist[i] = 0u;
    __syncthreads();
    const int* arr = ei + a * NE + s * SLE;
    int lo = c * 25000;
    for (int i = tid; i < SLE; i += 256) {
        int v = arr[i] - lo;
        if ((unsigned)v < 25000u)
            atomicAdd(&hist[v >> 1], 1u << ((v & 1) * 16));
    }
    __syncthreads();
    unsigned* dst = phist + (size_t)b * PW;
    for (int i = tid; i < PW; i += 256) dst[i] = hist[i];
}

__global__ __launch_bounds__(256) void k_hreduce(const unsigned* __restrict__ phist,
                                                 float* __restrict__ dinv,
                                                 int* __restrict__ cnt,
                                                 unsigned* __restrict__ pre) {
    int idx = blockIdx.x * 256 + threadIdx.x;
    if (idx >= 50000) return;
    int a = idx / 25000;
    int gw = idx % 25000;
    int c = gw / PW;
    int w = gw % PW;
    unsigned accLo = 0, accHi = 0;
    for (int s = 0; s < NSL; s++) {
        unsigned p = phist[(size_t)(((a * NSL + s) * 2 + c)) * PW + w];
        if (a == 1) pre[(size_t)s * 25000 + gw] = accLo | (accHi << 16);
        accLo += p & 0xffffu;
        accHi += p >> 16;
    }
    int b0 = c * 25000 + 2 * w;
    if (a == 0) {
        dinv[b0]     = accLo ? rsqrtf((float)accLo) : 0.0f;
        dinv[b0 + 1] = accHi ? rsqrtf((float)accHi) : 0.0f;
    } else {
        cnt[b0]     = (int)accLo;
        cnt[b0 + 1] = (int)accHi;
    }
}

__global__ __launch_bounds__(1024) void k_scan1(const int* __restrict__ cnt,
                                                int* __restrict__ rowptr,
                                                int* __restrict__ bsum) {
    __shared__ int s[1024];
    int tid = threadIdx.x;
    int gid = blockIdx.x * 1024 + tid;
    int v = (gid < NN) ? cnt[gid] : 0;
    s[tid] = v;
    __syncthreads();
    for (int off = 1; off < 1024; off <<= 1) {
        int t = 0;
        if (tid >= off) t = s[tid - off];
        __syncthreads();
        s[tid] += t;
        __syncthreads();
    }
    if (gid < NN) rowptr[gid] = s[tid] - v;
    if (tid == 1023) bsum[blockIdx.x] = s[1023];
}

// wave-parallel 64-element exclusive scan
__global__ void k_scan2(const int* __restrict__ bsum, int* __restrict__ boff,
                        int nb, int* __restrict__ rowptr) {
    int lane = threadIdx.x;  // 64 threads, one wave
    int v = (lane < nb) ? bsum[lane] : 0;
    int s = v;
    #pragma unroll
    for (int off = 1; off < 64; off <<= 1) {
        int t = __shfl_up(s, off, 64);
        if (lane >= off) s += t;
    }
    if (lane < nb) boff[lane] = s - v;
    if (lane == 63) rowptr[NN] = s;
}

__global__ void k_scan3(int* __restrict__ rowptr, const int* __restrict__ boff) {
    int i = blockIdx.x * 256 + threadIdx.x;
    if (i < NN) rowptr[i] += boff[i >> 10];
}

__global__ __launch_bounds__(256) void k_fill2(const int* __restrict__ ei,
                                               const float* __restrict__ dinv,
                                               const int* __restrict__ rowptr,
                                               const unsigned* __restrict__ pre,
                                               unsigned* __restrict__ edg) {
    __shared__ unsigned rank[PW];  // 50 KB
    int b = blockIdx.x;
    int s = b >> 1;
    int c = b & 1;
    int tid = threadIdx.x;
    for (int i = tid; i < PW; i += 256) rank[i] = 0u;
    __syncthreads();
    int lo = c * 25000;
    const unsigned* preS = pre + (size_t)s * 25000 + c * PW;
    for (int i = tid; i < SLE; i += 256) {
        int e = s * SLE + i;
        int d = ei[NE + e];
        int v = d - lo;
        if ((unsigned)v < 25000u) {
            int src = ei[e];
            int w = v >> 1;
            int sh = (v & 1) * 16;
            unsigned r = atomicAdd(&rank[w], 1u << sh);
            r = (r >> sh) & 0xffffu;
            unsigned pw = (preS[w] >> sh) & 0xffffu;
            int pos = rowptr[d] + (int)pw + (int)r;
            unsigned short hw = __half_as_ushort(__float2half(-dinv[src] * dinv[d]));
            edg[pos] = (unsigned)src | ((unsigned)hw << 16);
        }
    }
}

// ---------------------------------------------------------------------------
// Propagation dim-3 (fp32, layer 1 only). 4-edge unroll + masked tail.
// ---------------------------------------------------------------------------
__global__ __launch_bounds__(128) void k_prop3(const float* __restrict__ h,
                        const float* __restrict__ sub,
                        const int* __restrict__ rowptr, const unsigned* __restrict__ edg,
                        float* __restrict__ out) {
    int node = blockIdx.x * 128 + threadIdx.x;
    if (node >= NN) return;
    int e0 = rowptr[node], e1 = rowptr[node + 1];
    float a0 = 0.f, a1 = 0.f, a2 = 0.f;
    float c0 = 0.f, c1 = 0.f, c2 = 0.f;
    int e = e0;
    for (; e + 4 <= e1; e += 4) {
        unsigned p0 = edg[e], p1 = edg[e + 1], p2 = edg[e + 2], p3 = edg[e + 3];
        int s0 = (int)(p0 & 0xffffu) * 3, s1 = (int)(p1 & 0xffffu) * 3;
        int s2 = (int)(p2 & 0xffffu) * 3, s3 = (int)(p3 & 0xffffu) * 3;
        float x0 = h[s0], y0 = h[s0 + 1], z0 = h[s0 + 2];
        float x1 = h[s1], y1 = h[s1 + 1], z1 = h[s1 + 2];
        float x2 = h[s2], y2 = h[s2 + 1], z2 = h[s2 + 2];
        float x3 = h[s3], y3 = h[s3 + 1], z3 = h[s3 + 2];
        float w0 = edgw(p0), w1 = edgw(p1), w2 = edgw(p2), w3 = edgw(p3);
        a0 = fmaf(w0, x0, a0); a1 = fmaf(w0, y0, a1); a2 = fmaf(w0, z0, a2);
        c0 = fmaf(w1, x1, c0); c1 = fmaf(w1, y1, c1); c2 = fmaf(w1, z1, c2);
        a0 = fmaf(w2, x2, a0); a1 = fmaf(w2, y2, a1); a2 = fmaf(w2, z2, a2);
        c0 = fmaf(w3, x3, c0); c1 = fmaf(w3, y3, c1); c2 = fmaf(w3, z3, c2);
    }
    if (e < e1) {  // masked 3-wide tail: packed 0 -> src 0, weight 0.0 (exact no-op)
        unsigned p0 = edg[e];
        unsigned p1 = (e + 1 < e1) ? edg[e + 1] : 0u;
        unsigned p2 = (e + 2 < e1) ? edg[e + 2] : 0u;
        int s0 = (int)(p0 & 0xffffu) * 3, s1 = (int)(p1 & 0xffffu) * 3;
        int s2 = (int)(p2 & 0xffffu) * 3;
        float x0 = h[s0], y0 = h[s0 + 1], z0 = h[s0 + 2];
        float x1 = h[s1], y1 = h[s1 + 1], z1 = h[s1 + 2];
        float x2 = h[s2], y2 = h[s2 + 1], z2 = h[s2 + 2];
        float w0 = edgw(p0), w1 = edgw(p1), w2 = edgw(p2);
        a0 = fmaf(w0, x0, a0); a1 = fmaf(w0, y0, a1); a2 = fmaf(w0, z0, a2);
        c0 = fmaf(w1, x1, c0); c1 = fmaf(w1, y1, c1); c2 = fmaf(w1, z1, c2);
        a0 = fmaf(w2, x2, a0); a1 = fmaf(w2, y2, a1); a2 = fmaf(w2, z2, a2);
    }
    a0 += c0; a1 += c1; a2 += c2;
    if (sub) {
        a0 = 2.f * a0 - sub[node * 3 + 0];
        a1 = 2.f * a1 - sub[node * 3 + 1];
        a2 = 2.f * a2 - sub[node * 3 + 2];
    }
    out[node * 3 + 0] = a0;
    out[node * 3 + 1] = a1;
    out[node * 3 + 2] = a2;
}

// ---------------------------------------------------------------------------
// Propagation dim-128, feature-planar bf16 [plane 0..3][node][32].
// XCD-pinned chunks; 8-edge unroll. Edge packet loads go through the NORMAL
// cache path (R6 post-mortem: NT edge loads forced HBM latency onto the
// serial chain, -80us) but are SOFTWARE-PIPELINED one iteration ahead
// (removes the ~200cy L2 edge-load latency from the chain). +8-word edg pad
// bounds prefetch over-reads; tail consumes the prefetched value (rem-
// sanitized, bit-identical results).
// ---------------------------------------------------------------------------
#define ACC8(acc, u, v)                                               \
    acc[0] = fmaf(v, __uint_as_float(u[0] << 16), acc[0]);            \
    acc[1] = fmaf(v, __uint_as_float(u[0] & 0xffff0000u), acc[1]);    \
    acc[2] = fmaf(v, __uint_as_float(u[1] << 16), acc[2]);            \
    acc[3] = fmaf(v, __uint_as_float(u[1] & 0xffff0000u), acc[3]);    \
    acc[4] = fmaf(v, __uint_as_float(u[2] << 16), acc[4]);            \
    acc[5] = fmaf(v, __uint_as_float(u[2] & 0xffff0000u), acc[5]);    \
    acc[6] = fmaf(v, __uint_as_float(u[3] << 16), acc[6]);            \
    acc[7] = fmaf(v, __uint_as_float(u[3] & 0xffff0000u), acc[7]);

__global__ __launch_bounds__(256) void k_prop_pl(
        const unsigned short* __restrict__ h, const unsigned short* __restrict__ sub,
        const int* __restrict__ rowptr, const unsigned* __restrict__ edg,
        unsigned short* __restrict__ out) {
    int B = blockIdx.x;
    int xcd = B & 7;
    int c = xcd >> 1;        // chunk pinned to XCD pair
    int half = xcd & 1;      // node-range half
    int g = B >> 3;          // 0..391
    int n = (half * 392 + g) * 64 + (threadIdx.x >> 2);
    if (n >= NN) return;
    int lane4 = threadIdx.x & 3;
    int sl = lane4 * 8;                       // ushort slice offset
    int base = (threadIdx.x & 63) & ~3;       // node's first lane in wave
    const unsigned short* hp = h + (size_t)c * (NN * 32);
    int e0 = rowptr[n], e1 = rowptr[n + 1];
    float a[8] = {0, 0, 0, 0, 0, 0, 0, 0};
    float b[8] = {0, 0, 0, 0, 0, 0, 0, 0};
    int e = e0;
    // prefetch first 8-edge packet (pad-bounded; unused if row empty)
    u32x2 pp = *(const u32x2*)(edg + e + lane4 * 2);
    for (; e + 8 <= e1; e += 8) {
        u32x2 cur = pp;
        pp = *(const u32x2*)(edg + e + 8 + lane4 * 2);
        unsigned q0 = __shfl(cur[0], base + 0, 64);
        unsigned q1 = __shfl(cur[1], base + 0, 64);
        unsigned q2 = __shfl(cur[0], base + 1, 64);
        unsigned q3 = __shfl(cur[1], base + 1, 64);
        unsigned q4 = __shfl(cur[0], base + 2, 64);
        unsigned q5 = __shfl(cur[1], base + 2, 64);
        unsigned q6 = __shfl(cur[0], base + 3, 64);
        unsigned q7 = __shfl(cur[1], base + 3, 64);
        u32x4 u0 = *(const u32x4*)(hp + (q0 & 0xffffu) * 32 + sl);
        u32x4 u1 = *(const u32x4*)(hp + (q1 & 0xffffu) * 32 + sl);
        u32x4 u2 = *(const u32x4*)(hp + (q2 & 0xffffu) * 32 + sl);
        u32x4 u3 = *(const u32x4*)(hp + (q3 & 0xffffu) * 32 + sl);
        u32x4 u4 = *(const u32x4*)(hp + (q4 & 0xffffu) * 32 + sl);
        u32x4 u5 = *(const u32x4*)(hp + (q5 & 0xffffu) * 32 + sl);
        u32x4 u6 = *(const u32x4*)(hp + (q6 & 0xffffu) * 32 + sl);
        u32x4 u7 = *(const u32x4*)(hp + (q7 & 0xffffu) * 32 + sl);
        float v0 = edgw(q0), v1 = edgw(q1), v2 = edgw(q2), v3 = edgw(q3);
        float v4 = edgw(q4), v5 = edgw(q5), v6 = edgw(q6), v7 = edgw(q7);
        ACC8(a, u0, v0)
        ACC8(b, u1, v1)
        ACC8(a, u2, v2)
        ACC8(b, u3, v3)
        ACC8(a, u4, v4)
        ACC8(b, u5, v5)
        ACC8(a, u6, v6)
        ACC8(b, u7, v7)
    }
    int rem = e1 - e;        // 0..7
    if (rem > 0) {
        // pp already holds the tail packet (prefetched); sanitize beyond rem
        unsigned q0 = __shfl(pp[0], base + 0, 64);
        unsigned q1 = __shfl(pp[1], base + 0, 64);
        unsigned q2 = __shfl(pp[0], base + 1, 64);
        unsigned q3 = __shfl(pp[1], base + 1, 64);
        unsigned q4 = __shfl(pp[0], base + 2, 64);
        unsigned q5 = __shfl(pp[1], base + 2, 64);
        unsigned q6 = __shfl(pp[0], base + 3, 64);
        unsigned q7 = __shfl(pp[1], base + 3, 64);
        q1 = (rem > 1) ? q1 : 0u;
        q2 = (rem > 2) ? q2 : 0u;
        q3 = (rem > 3) ? q3 : 0u;
        q4 = (rem > 4) ? q4 : 0u;
        q5 = (rem > 5) ? q5 : 0u;
        q6 = (rem > 6) ? q6 : 0u;
        q7 = 0u;
        u32x4 u0 = *(const u32x4*)(hp + (q0 & 0xffffu) * 32 + sl);
        u32x4 u1 = *(const u32x4*)(hp + (q1 & 0xffffu) * 32 + sl);
        u32x4 u2 = *(const u32x4*)(hp + (q2 & 0xffffu) * 32 + sl);
        u32x4 u3 = *(const u32x4*)(hp + (q3 & 0xffffu) * 32 + sl);
        u32x4 u4 = *(const u32x4*)(hp + (q4 & 0xffffu) * 32 + sl);
        u32x4 u5 = *(const u32x4*)(hp + (q5 & 0xffffu) * 32 + sl);
        u32x4 u6 = *(const u32x4*)(hp + (q6 & 0xffffu) * 32 + sl);
        u32x4 u7 = *(const u32x4*)(hp + (q7 & 0xffffu) * 32 + sl);
        float v0 = edgw(q0), v1 = edgw(q1), v2 = edgw(q2), v3 = edgw(q3);
        float v4 = edgw(q4), v5 = edgw(q5), v6 = edgw(q6), v7 = edgw(q7);
        ACC8(a, u0, v0)
        ACC8(b, u1, v1)
        ACC8(a, u2, v2)
        ACC8(b, u3, v3)
        ACC8(a, u4, v4)
        ACC8(b, u5, v5)
        ACC8(a, u6, v6)
        ACC8(b, u7, v7)
    }
    float r[8];
    #pragma unroll
    for (int q = 0; q < 8; q++) r[q] = a[q] + b[q];
    if (sub) {
        u32x4 su = __builtin_nontemporal_load(
            (const u32x4*)(sub + (size_t)c * (NN * 32) + n * 32 + sl));
        float s[8];
        s[0] = __uint_as_float(su[0] << 16); s[1] = __uint_as_float(su[0] & 0xffff0000u);
        s[2] = __uint_as_float(su[1] << 16); s[3] = __uint_as_float(su[1] & 0xffff0000u);
        s[4] = __uint_as_float(su[2] << 16); s[5] = __uint_as_float(su[2] & 0xffff0000u);
        s[6] = __uint_as_float(su[3] << 16); s[7] = __uint_as_float(su[3] & 0xffff0000u);
        #pragma unroll
        for (int q = 0; q < 8; q++) r[q] = 2.f * r[q] - s[q];
    }
    u32x4 o;
    o[0] = bf2pack(r[0], r[1]);
    o[1] = bf2pack(r[2], r[3]);
    o[2] = bf2pack(r[4], r[5]);
    o[3] = bf2pack(r[6], r[7]);
    __builtin_nontemporal_store(o, (u32x4*)(out + (size_t)c * (NN * 32) + n * 32 + sl));
}

// ---------------------------------------------------------------------------
// W swizzle fp32 -> bf16 B-fragment order for all three 128x128 weights.
// ---------------------------------------------------------------------------
__global__ void k_wconv_all(const float* __restrict__ W2, const float* __restrict__ W3,
                            const float* __restrict__ W4, unsigned short* __restrict__ Wb) {
    int gidx = blockIdx.x * 256 + threadIdx.x;  // 0..196607
    int which = gidx >> 16;
    int idx = gidx & 65535;
    const float* W = which == 0 ? W2 : (which == 1 ? W3 : W4);
    int slot = idx >> 9;
    int lane = (idx >> 3) & 63;
    int j = idx & 7;
    int wg = slot >> 4;
    int t = slot & 15;
    int w = wg >> 1;
    int g = wg & 1;
    int k = t * 32 + (lane >> 4) * 8 + j;
    int col = w * 32 + g * 16 + (lane & 15);
    unsigned u = __float_as_uint(W[k * HD + col]);
    Wb[which * 65536 + idx] = (unsigned short)((u + 0x7fffu + ((u >> 16) & 1u)) >> 16);
}

// ---------------------------------------------------------------------------
// MFMA GEMM. A staged per 16-row tile into LDS (fragment order); B register-
// resident. act: 0=none, 1=leaky, 2=relu, 3=none+fused row-L2-normalize
// (layer 4: outF is the FINAL output). Fused BN partials -> gpart[col][512].
// ---------------------------------------------------------------------------
__global__ __launch_bounds__(256) void k_gemmM(
        const unsigned short* __restrict__ A0, const unsigned short* __restrict__ A1,
        const unsigned short* __restrict__ A2, const unsigned short* __restrict__ A3,
        const unsigned short* __restrict__ Wb, const float* __restrict__ bias,
        float* __restrict__ outF, int act, float* __restrict__ gpart) {
    __shared__ unsigned short Asm[16 * 64 * 8];  // 16 KB
    __shared__ float sred[64];                   // l2-mode cross-wave row sums
    const int tid = threadIdx.x;
    const int w = tid >> 6;
    const int lane = tid & 63;
    const int l15 = lane & 15;
    const int quad = lane >> 4;

    short8 Bf[16][2];
    #pragma unroll
    for (int t = 0; t < 16; t++) {
        #pragma unroll
        for (int g = 0; g < 2; g++) {
            int slot = (w * 2 + g) * 16 + t;
            Bf[t][g] = *(const short8*)(Wb + slot * 512 + lane * 8);
        }
    }
    float bcol[2];
    bcol[0] = bias[w * 32 + l15];
    bcol[1] = bias[w * 32 + 16 + l15];

    const unsigned short* Ap[4] = {A0, A1, A2, A3};
    float bnP[2] = {0.f, 0.f}, bnQ[2] = {0.f, 0.f};

    for (int tile = blockIdx.x; tile < NN / 16; tile += gridDim.x) {
        int r0 = tile * 16;
        __syncthreads();
        #pragma unroll
        for (int i = 0; i < 4; i++) {
            int idx = i * 256 + tid;          // 0..1023
            int s = idx >> 6;                 // frag slot 0..15
            int ln = idx & 63;
            const unsigned short* src = Ap[s >> 2] + (size_t)(s & 3) * (NN * 32)
                                        + (r0 + (ln & 15)) * 32 + (ln >> 4) * 8;
            *(uint4*)&Asm[idx * 8] = *(const uint4*)src;
        }
        __syncthreads();
        f32x4 acc0 = {0.f, 0.f, 0.f, 0.f};
        f32x4 acc1 = {0.f, 0.f, 0.f, 0.f};
        #pragma unroll
        for (int s = 0; s < 16; s++) {
            short8 af = *(const short8*)&Asm[(s * 64 + lane) * 8];
            acc0 = __builtin_amdgcn_mfma_f32_16x16x32_bf16(af, Bf[s][0], acc0, 0, 0, 0);
            acc1 = __builtin_amdgcn_mfma_f32_16x16x32_bf16(af, Bf[s][1], acc1, 0, 0, 0);
        }
        if (act == 3) {
            // ---- fused row L2 normalize; write final output ----
            float vv0[4], vv1[4], rs[4];
            #pragma unroll
            for (int reg = 0; reg < 4; reg++) {
                float v0 = acc0[reg] + bcol[0];
                float v1 = acc1[reg] + bcol[1];
                vv0[reg] = v0; vv1[reg] = v1;
                float s2 = v0 * v0 + v1 * v1;
                s2 += __shfl_xor(s2, 1);
                s2 += __shfl_xor(s2, 2);
                s2 += __shfl_xor(s2, 4);
                s2 += __shfl_xor(s2, 8);
                rs[reg] = s2;  // this wave's 32-col partial for row quad*4+reg
            }
            if (l15 == 0) {
                #pragma unroll
                for (int reg = 0; reg < 4; reg++)
                    sred[w * 16 + quad * 4 + reg] = rs[reg];
            }
            __syncthreads();
            #pragma unroll
            for (int reg = 0; reg < 4; reg++) {
                int row16 = quad * 4 + reg;
                float tot = sred[row16] + sred[16 + row16]
                          + sred[32 + row16] + sred[48 + row16];
                float sc = 1.f / fmaxf(sqrtf(tot), 1e-12f);
                int row = r0 + row16;
                outF[row * HD + w * 32 + l15] = vv0[reg] * sc;
                outF[row * HD + w * 32 + 16 + l15] = vv1[reg] * sc;
            }
        } else {
            #pragma unroll
            for (int reg = 0; reg < 4; reg++) {
                int row = r0 + quad * 4 + reg;
                float v0 = acc0[reg] + bcol[0];
                float v1 = acc1[reg] + bcol[1];
                if (act == 1) {
                    v0 = v0 > 0.f ? v0 : 0.01f * v0;
                    v1 = v1 > 0.f ? v1 : 0.01f * v1;
                } else if (act == 2) {
                    v0 = v0 > 0.f ? v0 : 0.f;
                    v1 = v1 > 0.f ? v1 : 0.f;
                }
                outF[row * HD + w * 32 + l15] = v0;
                outF[row * HD + w * 32 + 16 + l15] = v1;
                bnP[0] += v0; bnQ[0] += v0 * v0;
                bnP[1] += v1; bnQ[1] += v1 * v1;
            }
        }
    }
    if (gpart) {
        #pragma unroll
        for (int g = 0; g < 2; g++) {
            float p = bnP[g], q = bnQ[g];
            p += __shfl_xor(p, 16); p += __shfl_xor(p, 32);
            q += __shfl_xor(q, 16); q += __shfl_xor(q, 32);
            if (quad == 0) {
                int col = w * 32 + g * 16 + l15;
                gpart[col * 512 + blockIdx.x] = p;
                gpart[(128 + col) * 512 + blockIdx.x] = q;
            }
        }
    }
}

// ---------------------------------------------------------------------------
// Layer-1 GEMM: [N,3] x4 Cheb terms @ W1[4][3][128] + b, leaky relu -> fp32,
// with FUSED BN partial sums.
// ---------------------------------------------------------------------------
__global__ __launch_bounds__(256) void k_gemm1(
        const float* __restrict__ T0, const float* __restrict__ T1,
        const float* __restrict__ T2, const float* __restrict__ T3,
        const float* __restrict__ W, const float* __restrict__ bias,
        float* __restrict__ out, float* __restrict__ gpart) {
    __shared__ float Ws[12 * 128];
    __shared__ float red[512];
    int t = threadIdx.x;
    for (int i = t; i < 12 * 128; i += 256) Ws[i] = W[i];
    __syncthreads();
    int f = t & 127;
    int half = t >> 7;
    float bs = bias[f];
    float bP = 0.f, bQ = 0.f;
    int r0 = blockIdx.x * 98;
    int r1 = r0 + 98;
    if (r1 > NN) r1 = NN;
    const float* Ts[4] = {T0, T1, T2, T3};
    for (int n = r0 + half; n < r1; n += 2) {
        float acc = bs;
        #pragma unroll
        for (int c = 0; c < 12; c++) {
            float tv = Ts[c / 3][n * 3 + (c % 3)];
            acc = fmaf(tv, Ws[c * 128 + f], acc);
        }
        acc = acc > 0.f ? acc : 0.01f * acc;
        out[n * HD + f] = acc;
        bP += acc;
        bQ += acc * acc;
    }
    red[t] = bP;
    red[256 + t] = bQ;
    __syncthreads();
    if (t < 128) {
        gpart[t * 512 + blockIdx.x] = red[t] + red[t + 128];
        gpart[(128 + t) * 512 + blockIdx.x] = red[256 + t] + red[256 + t + 128];
    }
}

__global__ __launch_bounds__(128) void k_bnredfin(const float* __restrict__ gpart,
                                                  const float* __restrict__ g,
                                                  const float* __restrict__ be,
                                                  float* __restrict__ ss) {
    __shared__ float sm[2];
    int f = blockIdx.x;            // 0..127
    int wave = threadIdx.x >> 6;   // 0: sum, 1: sumsq
    int lane = threadIdx.x & 63;
    const float* src = gpart + (size_t)(f + wave * 128) * 512;
    float s = 0.f;
    #pragma unroll
    for (int i = 0; i < 8; i++) s += src[i * 64 + lane];
    #pragma unroll
    for (int off = 32; off > 0; off >>= 1) s += __shfl_xor(s, off);
    if (lane == 0) sm[wave] = s;
    __syncthreads();
    if (threadIdx.x == 0) {
        float mean = sm[0] * (1.0f / NN);
        float var = sm[1] * (1.0f / NN) - mean * mean;
        float sc = g[f] * rsqrtf(var + 1e-5f);
        ss[f] = sc;
        ss[128 + f] = be[f] - mean * sc;
    }
}

// BN apply on fp32 row-major src -> bf16 feature-planar out
__global__ void k_bncvt_pl(const float* __restrict__ h, const float* __restrict__ ss,
                           unsigned short* __restrict__ out) {
    int idx = blockIdx.x * 256 + threadIdx.x;  // over NN*16 chunks of 8 feats
    if (idx < NN * 16) {
        int n = idx >> 4;
        int p = (idx >> 2) & 3;
        int q = idx & 3;
        const float4* hf = (const float4*)h;
        float4 v0 = hf[n * 32 + p * 8 + q * 2];
        float4 v1 = hf[n * 32 + p * 8 + q * 2 + 1];
        const float4* s4 = (const float4*)ss;
        float4 c0 = s4[p * 8 + q * 2];
        float4 c1 = s4[p * 8 + q * 2 + 1];
        float4 d0 = s4[32 + p * 8 + q * 2];
        float4 d1 = s4[32 + p * 8 + q * 2 + 1];
        v0.x = fmaf(v0.x, c0.x, d0.x); v0.y = fmaf(v0.y, c0.y, d0.y);
        v0.z = fmaf(v0.z, c0.z, d0.z); v0.w = fmaf(v0.w, c0.w, d0.w);
        v1.x = fmaf(v1.x, c1.x, d1.x); v1.y = fmaf(v1.y, c1.y, d1.y);
        v1.z = fmaf(v1.z, c1.z, d1.z); v1.w = fmaf(v1.w, c1.w, d1.w);
        uint4 o;
        o.x = bf2pack(v0.x, v0.y);
        o.y = bf2pack(v0.z, v0.w);
        o.z = bf2pack(v1.x, v1.y);
        o.w = bf2pack(v1.z, v1.w);
        ((uint4*)out)[(size_t)p * (NN * 4) + n * 4 + q] = o;
    }
}

// ---------------------------------------------------------------------------
// Launch
// ---------------------------------------------------------------------------
extern "C" void kernel_launch(void* const* d_in, const int* in_sizes, int n_in,
                              void* d_out, int out_size, void* d_ws, size_t ws_size,
                              hipStream_t stream) {
    const float* x  = (const float*)d_in[0];
    const int*   ei = (const int*)d_in[1];
    const float* W1 = (const float*)d_in[2];
    const float* b1 = (const float*)d_in[3];
    const float* W2 = (const float*)d_in[4];
    const float* b2 = (const float*)d_in[5];
    const float* W3 = (const float*)d_in[6];
    const float* b3 = (const float*)d_in[7];
    const float* W4 = (const float*)d_in[8];
    const float* b4 = (const float*)d_in[9];
    const float* g1 = (const float*)d_in[10];
    const float* be1 = (const float*)d_in[11];
    const float* g2 = (const float*)d_in[12];
    const float* be2 = (const float*)d_in[13];
    const float* g3 = (const float*)d_in[14];
    const float* be3 = (const float*)d_in[15];
    float* outp = (float*)d_out;

    char* base = (char*)d_ws;
    size_t off = 0;
    auto alloc = [&](size_t bytes) -> void* {
        void* p = base + off;
        off += (bytes + 255) & ~(size_t)255;
        return p;
    };
    float* dinv  = (float*)alloc(NN * 4);
    int*   cnt   = (int*)  alloc(NN * 4);
    int*   rowptr= (int*)  alloc((NN + 1) * 4);
    int*   bsum  = (int*)  alloc(64 * 4);
    int*   boff  = (int*)  alloc(64 * 4);
    float* ss    = (float*)alloc(256 * 4);
    float* gpart = (float*)alloc(256 * 512 * 4);
    unsigned short* Wb = (unsigned short*)alloc(3 * 512 * 128 * 2);
    unsigned* edg = (unsigned*)alloc((size_t)(NE + 8) * 4);  // +8 pad for masked tail
    float* T3a   = (float*)alloc(NN * 3 * 4);
    float* T3b   = (float*)alloc(NN * 3 * 4);
    float* T3c   = (float*)alloc(NN * 3 * 4);
    float* F0    = (float*)alloc((size_t)NN * HD * 4);
    unsigned short* Bb0 = (unsigned short*)alloc((size_t)NN * HD * 2);
    unsigned short* Bb1 = (unsigned short*)alloc((size_t)NN * HD * 2);
    unsigned short* Bb2 = (unsigned short*)alloc((size_t)NN * HD * 2);
    unsigned short* Bb3 = (unsigned short*)alloc((size_t)NN * HD * 2);

    // overlays (consumed before their host slabs are first written):
    unsigned* pre   = (unsigned*)F0;    // 12.8 MB, freed by k_fill2
    unsigned* phist = (unsigned*)Bb0;   // 25.6 MB (Bb0+Bb1), freed by k_hreduce

    const int gN = (NN + 255) / 256;
    const int gP3 = (NN + 127) / 128;
    const int nb = (NN + 1023) / 1024;

    // ---- graph prep (no global atomics) ----
    k_hist<<<512, 256, 0, stream>>>(ei, phist);
    k_hreduce<<<(50000 + 255) / 256, 256, 0, stream>>>(phist, dinv, cnt, pre);
    k_scan1<<<nb, 1024, 0, stream>>>(cnt, rowptr, bsum);
    k_scan2<<<1, 64, 0, stream>>>(bsum, boff, nb, rowptr);
    k_scan3<<<gN, 256, 0, stream>>>(rowptr, boff);
    k_fill2<<<256, 256, 0, stream>>>(ei, dinv, rowptr, pre, edg);
    k_wconv_all<<<768, 256, 0, stream>>>(W2, W3, W4, Wb);

    const int gPP = 8 * 392;         // XCD-pinned planar prop
    const int gG = 512;              // gemmM grid-stride blocks
    const int gCvt = NN * 16 / 256;  // 3125
    unsigned short* Wb2 = Wb;
    unsigned short* Wb3 = Wb + 65536;
    unsigned short* Wb4 = Wb + 131072;

    // ---- layer 1 (in: x [N,3], fp32) ----
    k_prop3<<<gP3, 128, 0, stream>>>(x, nullptr, rowptr, edg, T3a);
    k_prop3<<<gP3, 128, 0, stream>>>(T3a, x, rowptr, edg, T3b);
    k_prop3<<<gP3, 128, 0, stream>>>(T3b, T3a, rowptr, edg, T3c);
    k_gemm1<<<512, 256, 0, stream>>>(x, T3a, T3b, T3c, W1, b1, F0, gpart);
    k_bnredfin<<<128, 128, 0, stream>>>(gpart, g1, be1, ss);
    k_bncvt_pl<<<gCvt, 256, 0, stream>>>(F0, ss, Bb0);

    // ---- layer 2 ----
    k_prop_pl<<<gPP, 256, 0, stream>>>(Bb0, nullptr, rowptr, edg, Bb1);
    k_prop_pl<<<gPP, 256, 0, stream>>>(Bb1, Bb0, rowptr, edg, Bb2);
    k_prop_pl<<<gPP, 256, 0, stream>>>(Bb2, Bb1, rowptr, edg, Bb3);
    k_gemmM<<<gG, 256, 0, stream>>>(Bb0, Bb1, Bb2, Bb3, Wb2, b2, F0, 1, gpart);
    k_bnredfin<<<128, 128, 0, stream>>>(gpart, g2, be2, ss);
    k_bncvt_pl<<<gCvt, 256, 0, stream>>>(F0, ss, Bb0);

    // ---- layer 3 ----
    k_prop_pl<<<gPP, 256, 0, stream>>>(Bb0, nullptr, rowptr, edg, Bb1);
    k_prop_pl<<<gPP, 256, 0, stream>>>(Bb1, Bb0, rowptr, edg, Bb2);
    k_prop_pl<<<gPP, 256, 0, stream>>>(Bb2, Bb1, rowptr, edg, Bb3);
    k_gemmM<<<gG, 256, 0, stream>>>(Bb0, Bb1, Bb2, Bb3, Wb3, b3, F0, 2, gpart);
    k_bnredfin<<<128, 128, 0, stream>>>(gpart, g3, be3, ss);
    k_bncvt_pl<<<gCvt, 256, 0, stream>>>(F0, ss, Bb0);

    // ---- layer 4 (GEMM + fused row-L2-normalize -> final output) ----
    k_prop_pl<<<gPP, 256, 0, stream>>>(Bb0, nullptr, rowptr, edg, Bb1);
    k_prop_pl<<<gPP, 256, 0, stream>>>(Bb1, Bb0, rowptr, edg, Bb2);
    k_prop_pl<<<gPP, 256, 0, stream>>>(Bb2, Bb1, rowptr, edg, Bb3);
    k_gemmM<<<gG, 256, 0, stream>>>(Bb0, Bb1, Bb2, Bb3, Wb4, b4, outp, 3, nullptr);

    (void)n_in; (void)in_sizes; (void)out_size; (void)ws_size;
}